// Round 4
// baseline (219.441 us; speedup 1.0000x reference)
//
#include <hip/hip_runtime.h>
#include <math.h>

#define Bn 8
#define Hn 128
#define Pn 128
#define Ln 4096
#define LF 2049           // Ln/2 + 1
#define NROWS (Bn*Hn)     // 1024
#define NT 16             // frequency columns per mixmm block
#define NTILES 129        // ceil(2049/16) per batch
#define PLSZ 2048         // ushorts per data plane (16 x 128)
#define WPLSZ 16384       // ushorts per weight plane (128 x 128)

// LDS skew for FFT buffers: +1 float2 every 16 -> strided Stockham writes <=2-way
#define SKEW(a) ((a) + ((a) >> 4))
#define FBUF 2176          // SKEW(2047)+1 rounded up

typedef __attribute__((ext_vector_type(8))) short short8;
typedef __attribute__((ext_vector_type(4))) float f32x4;

// ---------------------------------------------------------------------------
// bf16 helpers
// ---------------------------------------------------------------------------
__device__ __forceinline__ unsigned short bf16_rne(float x) {
    unsigned u = __float_as_uint(x);
    unsigned r = u + 0x7FFFu + ((u >> 16) & 1u);
    return (unsigned short)(r >> 16);
}
__device__ __forceinline__ void bf16_split(float x, unsigned short& hi, unsigned short& lo) {
    hi = bf16_rne(x);
    float fhi = __uint_as_float(((unsigned)hi) << 16);
    lo = bf16_rne(x - fhi);
}

// ---------------------------------------------------------------------------
// prep: fold H-axis FFTs into weights; bf16 hi/lo planes, [m][k] row-major.
// Planes: 0 r_hi, 1 i_hi, 2 (-i)_hi, 3 r_lo, 4 i_lo, 5 (-i)_lo
//   W1[p][h] = (B_bar @ F)[p][h]
//   W2[h][p] = (Finv @ C)[h][p]
//   E [a][q] = (D @ F)[a][q]  (fp32 temp)
//   W3[h][q] = (Finv @ E)[h][q]
// ---------------------------------------------------------------------------
__device__ __forceinline__ void write6(unsigned short* __restrict__ W, int idx,
                                       float vr, float vi) {
    unsigned short rh, rl, ih, il, nh, nl;
    bf16_split(vr, rh, rl);
    bf16_split(vi, ih, il);
    bf16_split(-vi, nh, nl);
    W[0 * WPLSZ + idx] = rh;
    W[1 * WPLSZ + idx] = ih;
    W[2 * WPLSZ + idx] = nh;
    W[3 * WPLSZ + idx] = rl;
    W[4 * WPLSZ + idx] = il;
    W[5 * WPLSZ + idx] = nl;
}

__global__ void prep_ABE_k(const float* __restrict__ B_ri, const float* __restrict__ C_ri,
                           const float* __restrict__ D_ri,
                           unsigned short* __restrict__ W1, unsigned short* __restrict__ W2,
                           float2* __restrict__ E) {
    int bid = blockIdx.x;
    int idx = (bid & 63) * 256 + threadIdx.x;   // 0..16383
    int rrow = idx >> 7, ccol = idx & 127;
    if (bid < 64) {
        // W1[p][h], p=rrow h=ccol
        float sr = 0.f, si = 0.f;
        for (int q = 0; q < 128; ++q) {
            float br = B_ri[(rrow * 128 + q) * 2 + 0];
            float bi = B_ri[(rrow * 128 + q) * 2 + 1];
            float ang = -3.14159265358979f * (float)((q * ccol) & 127) / 64.0f;
            float sw, cw; __sincosf(ang, &sw, &cw);
            sr += br * cw - bi * sw;
            si += br * sw + bi * cw;
        }
        write6(W1, idx, sr, si);
    } else if (bid < 128) {
        // W2[h][p], h=rrow p=ccol
        float sr = 0.f, si = 0.f;
        for (int h2 = 0; h2 < 128; ++h2) {
            float cr = C_ri[(h2 * 128 + ccol) * 2 + 0];
            float ci = C_ri[(h2 * 128 + ccol) * 2 + 1];
            float ang = 3.14159265358979f * (float)((rrow * h2) & 127) / 64.0f;
            float sw, cw; __sincosf(ang, &sw, &cw);
            sr += cr * cw - ci * sw;
            si += cr * sw + ci * cw;
        }
        write6(W2, idx, sr * (1.0f / 128.0f), si * (1.0f / 128.0f));
    } else {
        // E[a][q], a=rrow q=ccol
        float sr = 0.f, si = 0.f;
        for (int c = 0; c < 128; ++c) {
            float dr = D_ri[(rrow * 128 + c) * 2 + 0];
            float di = D_ri[(rrow * 128 + c) * 2 + 1];
            float ang = -3.14159265358979f * (float)((c * ccol) & 127) / 64.0f;
            float sw, cw; __sincosf(ang, &sw, &cw);
            sr += dr * cw - di * sw;
            si += dr * sw + di * cw;
        }
        E[idx] = make_float2(sr, si);
    }
}

__global__ void prep_W3_k(const float2* __restrict__ E, unsigned short* __restrict__ W3) {
    int idx = blockIdx.x * blockDim.x + threadIdx.x;   // h*128 + q
    int h = idx >> 7, q = idx & 127;
    float sr = 0.f, si = 0.f;
    for (int a = 0; a < 128; ++a) {
        float2 e = E[a * 128 + q];
        float ang = 3.14159265358979f * (float)((h * a) & 127) / 64.0f;
        float sw, cw; __sincosf(ang, &sw, &cw);
        sr += e.x * cw - e.y * sw;
        si += e.x * sw + e.y * cw;
    }
    write6(W3, idx, sr * (1.0f / 128.0f), si * (1.0f / 128.0f));
}

// ---------------------------------------------------------------------------
// 2048-pt Stockham FFT in LDS: radix-8 x3 + radix-4 (final, twiddle-free).
// Schema (validated at radix-4 in rounds 2-3):
//   dst[q+(Rp+j)s] = (sum_u src[q+(p+um)s] w_R^{SIGN ju}) * e^{SIGN 2pi i j p s/N}
// Reads are always contiguous: src[k + u*N/R]. All addresses SKEWed.
// 256 threads; result ends in bufA.
// ---------------------------------------------------------------------------
__device__ __forceinline__ float2 cadd2(float2 a, float2 b) { return make_float2(a.x + b.x, a.y + b.y); }
__device__ __forceinline__ float2 csub2(float2 a, float2 b) { return make_float2(a.x - b.x, a.y - b.y); }

template <int SIGN>
__device__ __forceinline__ void dft4(float2 a0, float2 a1, float2 a2, float2 a3,
                                     float2& y0, float2& y1, float2& y2, float2& y3) {
    float t0x = a0.x + a2.x, t0y = a0.y + a2.y;
    float t1x = a0.x - a2.x, t1y = a0.y - a2.y;
    float t2x = a1.x + a3.x, t2y = a1.y + a3.y;
    float t3x = a1.x - a3.x, t3y = a1.y - a3.y;
    y0 = make_float2(t0x + t2x, t0y + t2y);
    y2 = make_float2(t0x - t2x, t0y - t2y);
    y1 = make_float2(t1x - (float)SIGN * t3y, t1y + (float)SIGN * t3x);
    y3 = make_float2(t1x + (float)SIGN * t3y, t1y - (float)SIGN * t3x);
}

template <int SIGN>
__device__ __forceinline__ void fft2048(float2* bufA, float2* bufB) {
    const int tid = threadIdx.x;
    float2* src = bufA;
    float2* dst = bufB;
    #pragma unroll
    for (int stg = 0; stg < 3; ++stg) {
        const int ls = 3 * stg;           // s = 8^stg
        const int k = tid;                // 256 butterflies
        const int q = k & ((1 << ls) - 1);
        const int p = k >> ls;
        float2 a[8];
        #pragma unroll
        for (int u = 0; u < 8; ++u) a[u] = src[SKEW(k + (u << 8))];
        float2 A0, A1, A2, A3, B0, B1, B2, B3;
        dft4<SIGN>(a[0], a[2], a[4], a[6], A0, A1, A2, A3);
        dft4<SIGN>(a[1], a[3], a[5], a[7], B0, B1, B2, B3);
        const float c45 = 0.70710678118655f;
        float2 w1 = make_float2(c45 * (B1.x - (float)SIGN * B1.y), c45 * ((float)SIGN * B1.x + B1.y));
        float2 w2 = make_float2(-(float)SIGN * B2.y, (float)SIGN * B2.x);
        float2 w3 = make_float2(c45 * (-B3.x - (float)SIGN * B3.y), c45 * ((float)SIGN * B3.x - B3.y));
        float2 b[8];
        b[0] = cadd2(A0, B0);  b[4] = csub2(A0, B0);
        b[1] = cadd2(A1, w1);  b[5] = csub2(A1, w1);
        b[2] = cadd2(A2, w2);  b[6] = csub2(A2, w2);
        b[3] = cadd2(A3, w3);  b[7] = csub2(A3, w3);
        float ang = (float)SIGN * 6.28318530717959f * (float)p * (1.0f / (float)(2048 >> ls));
        float s1, c1; __sincosf(ang, &s1, &c1);
        float cp = 1.f, sp = 0.f;
        #pragma unroll
        for (int j = 1; j < 8; ++j) {
            float cn = cp * c1 - sp * s1;
            float sn = cp * s1 + sp * c1;
            cp = cn; sp = sn;
            b[j] = make_float2(b[j].x * cp - b[j].y * sp, b[j].x * sp + b[j].y * cp);
        }
        const int base = q + (p << (ls + 3));
        #pragma unroll
        for (int j = 0; j < 8; ++j) dst[SKEW(base + (j << ls))] = b[j];
        __syncthreads();
        float2* t = src; src = dst; dst = t;
    }
    // final radix-4: s=512, m=1 -> p=0, twiddles = 1
    #pragma unroll
    for (int r = 0; r < 2; ++r) {
        int k = tid + (r << 8);
        float2 a0 = src[SKEW(k)];
        float2 a1 = src[SKEW(k + 512)];
        float2 a2 = src[SKEW(k + 1024)];
        float2 a3 = src[SKEW(k + 1536)];
        float2 y0, y1, y2, y3;
        dft4<SIGN>(a0, a1, a2, a3, y0, y1, y2, y3);
        dst[SKEW(k)] = y0;
        dst[SKEW(k + 512)] = y1;
        dst[SKEW(k + 1024)] = y2;
        dst[SKEW(k + 1536)] = y3;
    }
    __syncthreads();
    // stages: A->B, B->A, A->B, B->A  => result in bufA
}

// rfft via real-packing: z[n] = u[2n] + i u[2n+1]; U from Z by even/odd unpack.
__global__ __launch_bounds__(256, 4) void rfft_rows_k(const float* __restrict__ u,
                                                      float2* __restrict__ Uhat) {
    __shared__ __align__(16) float2 bufA[FBUF];
    __shared__ __align__(16) float2 bufB[FBUF];
    const int row = blockIdx.x;
    const int tid = threadIdx.x;
    const float2* up = (const float2*)(u + (size_t)row * Ln);
    for (int i = tid; i < 2048; i += 256) bufA[SKEW(i)] = up[i];
    __syncthreads();
    fft2048<-1>(bufA, bufB);
    float2* op = Uhat + (size_t)row * LF;
    for (int l = tid; l < 1025; l += 256) {
        float2 Zl = bufA[SKEW(l)];
        float2 Zm = bufA[SKEW((2048 - l) & 2047)];
        float2 Fe = make_float2(0.5f * (Zl.x + Zm.x), 0.5f * (Zl.y - Zm.y));
        float2 Dv = make_float2(0.5f * (Zl.x - Zm.x), 0.5f * (Zl.y + Zm.y));
        float2 Fo = make_float2(Dv.y, -Dv.x);                 // Dv / i
        float s, c; __sincosf(-3.14159265358979f * (float)l / 2048.0f, &s, &c);
        float2 TF = make_float2(Fo.x * c - Fo.y * s, Fo.x * s + Fo.y * c);
        op[l] = make_float2(Fe.x + TF.x, Fe.y + TF.y);
        op[2048 - l] = make_float2(Fe.x - TF.x, -(Fe.y - TF.y));   // conj(Fe - TF)
    }
}

// irfft via inverse packing: Z[l] = Fe + i Fo rebuilt from U, then 2048 IFFT,
// y[2n]=Re(z), y[2n+1]=Im(z), scale 1/2048, exact GELU.
__global__ __launch_bounds__(256, 4) void irfft_gelu_k(const float2* __restrict__ Uhat,
                                                       float* __restrict__ out) {
    __shared__ __align__(16) float2 bufA[FBUF];
    __shared__ __align__(16) float2 bufB[FBUF];
    const int row = blockIdx.x;
    const int tid = threadIdx.x;
    const float2* wp = Uhat + (size_t)row * LF;
    for (int l = tid; l < 1025; l += 256) {
        float2 Ul = wp[l];
        float2 Um = wp[2048 - l];
        float2 Fe = make_float2(0.5f * (Ul.x + Um.x), 0.5f * (Ul.y - Um.y));
        float2 Dv = make_float2(0.5f * (Ul.x - Um.x), 0.5f * (Ul.y + Um.y));
        float s, c; __sincosf(3.14159265358979f * (float)l / 2048.0f, &s, &c);
        float2 Fo = make_float2(Dv.x * c - Dv.y * s, Dv.x * s + Dv.y * c);
        bufA[SKEW(l)] = make_float2(Fe.x - Fo.y, Fe.y + Fo.x);          // Fe + i Fo
        if (l >= 1 && l <= 1023)
            bufA[SKEW(2048 - l)] = make_float2(Fe.x + Fo.y, Fo.x - Fe.y); // conj(Fe)+i conj(Fo)
    }
    __syncthreads();
    fft2048<1>(bufA, bufB);
    float2* op = (float2*)(out + (size_t)row * Ln);
    for (int n = tid; n < 2048; n += 256) {
        float2 z = bufA[SKEW(n)];
        float y0 = z.x * (1.0f / 2048.0f);
        float y1 = z.y * (1.0f / 2048.0f);
        op[n] = make_float2(0.5f * y0 * (1.0f + erff(y0 * 0.70710678118655f)),
                            0.5f * y1 * (1.0f + erff(y1 * 0.70710678118655f)));
    }
}

// ---------------------------------------------------------------------------
// mixmm: NT=16 frequency columns per block, one batch each; 32 KB LDS ->
// 5 blocks/CU (20 waves) for latency hiding. Grid 8*129=1032 <= 1280 slots.
//   T = B2 @ U ; T *= mid(p,l) ; W = C2 @ T + D2 @ U
// bf16 3-term hi/lo split; MFMA 16x16x32 bf16 (layouts verified r3).
// ---------------------------------------------------------------------------
__device__ __forceinline__ f32x4 mfma16(short8 a, short8 b, f32x4 c) {
    return __builtin_amdgcn_mfma_f32_16x16x32_bf16(a, b, c, 0, 0, 0);
}
__device__ __forceinline__ short8 read_frag(const unsigned short* plane, int n, int k) {
    int ksw = k ^ ((n & 7) << 3);
    return *(const short8*)(plane + n * 128 + ksw);
}
__device__ __forceinline__ short8 aread(const unsigned short* W, int pl, int m, int k) {
    return *(const short8*)(W + pl * WPLSZ + m * 128 + k);
}
__device__ __forceinline__ void cmfma12(const short8 A[6],
                                        short8 brh, short8 bih, short8 brl, short8 bil,
                                        f32x4& aR, f32x4& aI) {
    aR = mfma16(A[0], brh, aR);  aR = mfma16(A[2], bih, aR);   // hi*hi
    aR = mfma16(A[3], brh, aR);  aR = mfma16(A[5], bih, aR);   // lo*hi
    aR = mfma16(A[0], brl, aR);  aR = mfma16(A[2], bil, aR);   // hi*lo
    aI = mfma16(A[0], bih, aI);  aI = mfma16(A[1], brh, aI);
    aI = mfma16(A[3], bih, aI);  aI = mfma16(A[4], brh, aI);
    aI = mfma16(A[0], bil, aI);  aI = mfma16(A[1], brl, aI);
}

__global__ __launch_bounds__(256, 5) void mixmm_k(float2* __restrict__ Uhat,
                                                  const unsigned short* __restrict__ W1,
                                                  const unsigned short* __restrict__ W2,
                                                  const unsigned short* __restrict__ W3,
                                                  const float* __restrict__ Lam) {
    // data planes: 0 r_hi, 1 i_hi, 2 r_lo, 3 i_lo
    __shared__ __align__(16) unsigned short Up[4 * PLSZ];    // 16 KB
    __shared__ __align__(16) unsigned short TpU[4 * PLSZ];   // 16 KB (T planes / U fp32 stage)
    float2* Ustage = (float2*)TpU;                           // [128][16] overlay

    const int tid = threadIdx.x;
    const int b = blockIdx.x / NTILES;
    const int tile = blockIdx.x % NTILES;
    const int l0 = tile * NT;
    const int ncols = (LF - l0) < NT ? (LF - l0) : NT;

    // ---- load U tile ----
    for (int i = tid; i < 128 * NT; i += 256) {
        int h = i >> 4, n = i & 15;
        float2 v = make_float2(0.f, 0.f);
        if (n < ncols) v = Uhat[(size_t)(b * 128 + h) * LF + l0 + n];
        Ustage[h * NT + n] = v;
    }
    __syncthreads();

    // ---- convert to bf16 hi/lo planes [n][k=h], swizzled ----
    {
        int n = tid & 15, kc = tid >> 4;   // kc 0..15: h = kc*8 + j
        short8 rh, ih, rl, il;
        #pragma unroll
        for (int j = 0; j < 8; ++j) {
            int h = kc * 8 + j;
            float2 v = Ustage[h * NT + n];
            unsigned short a, bb, c, d;
            bf16_split(v.x, a, bb);
            bf16_split(v.y, c, d);
            rh[j] = (short)a; rl[j] = (short)bb;
            ih[j] = (short)c; il[j] = (short)d;
        }
        int k0 = kc * 8;
        int ksw = k0 ^ ((n & 7) << 3);
        *(short8*)(Up + 0 * PLSZ + n * 128 + ksw) = rh;
        *(short8*)(Up + 1 * PLSZ + n * 128 + ksw) = ih;
        *(short8*)(Up + 2 * PLSZ + n * 128 + ksw) = rl;
        *(short8*)(Up + 3 * PLSZ + n * 128 + ksw) = il;
    }
    __syncthreads();   // Up ready; Ustage consumed (TpU free for T planes)

    const int lane = tid & 63;
    const int w = tid >> 6;          // wave: rows w*32 .. w*32+31
    const int m15 = lane & 15;
    const int quad = lane >> 4;

    f32x4 aR[2], aI[2];
    #pragma unroll
    for (int s = 0; s < 2; ++s) { aR[s] = (f32x4)0.f; aI[s] = (f32x4)0.f; }

    // ---- stage 1: T = B2 @ U ----
    for (int kb = 0; kb < 4; ++kb) {
        int k = kb * 32 + quad * 8;
        int n = m15;
        short8 brh = read_frag(Up + 0 * PLSZ, n, k);
        short8 bih = read_frag(Up + 1 * PLSZ, n, k);
        short8 brl = read_frag(Up + 2 * PLSZ, n, k);
        short8 bil = read_frag(Up + 3 * PLSZ, n, k);
        #pragma unroll
        for (int s = 0; s < 2; ++s) {
            int m = w * 32 + s * 16 + m15;
            short8 A[6];
            #pragma unroll
            for (int pl = 0; pl < 6; ++pl) A[pl] = aread(W1, pl, m, k);
            cmfma12(A, brh, bih, brl, bil, aR[s], aI[s]);
        }
    }

    // ---- Cauchy scale + write T planes ----
    #pragma unroll
    for (int s = 0; s < 2; ++s) {
        #pragma unroll
        for (int reg = 0; reg < 4; ++reg) {
            int p = w * 32 + s * 16 + quad * 4 + reg;
            float2 lamv = ((const float2*)Lam)[p];
            float dr = -lamv.x;
            int n = m15;
            int l = l0 + n;
            float di = 3.14159265358979f * (float)l / 2048.0f - lamv.y;
            float inv = 1.0f / (dr * dr + di * di);
            float xr = aR[s][reg], xi = aI[s][reg];
            float tr = (xr * dr + xi * di) * inv;
            float ti = (xi * dr - xr * di) * inv;
            unsigned short trh, trl, tih, til;
            bf16_split(tr, trh, trl);
            bf16_split(ti, tih, til);
            int off = n * 128 + (p ^ ((n & 7) << 3));
            TpU[0 * PLSZ + off] = trh;
            TpU[1 * PLSZ + off] = tih;
            TpU[2 * PLSZ + off] = trl;
            TpU[3 * PLSZ + off] = til;
        }
    }
    __syncthreads();   // T planes visible

    // ---- stage 2: W = C2 @ T + D2 @ U ----
    #pragma unroll
    for (int s = 0; s < 2; ++s) { aR[s] = (f32x4)0.f; aI[s] = (f32x4)0.f; }

    for (int kb = 0; kb < 4; ++kb) {
        int k = kb * 32 + quad * 8;
        int n = m15;
        short8 trh = read_frag(TpU + 0 * PLSZ, n, k);
        short8 tih = read_frag(TpU + 1 * PLSZ, n, k);
        short8 trl = read_frag(TpU + 2 * PLSZ, n, k);
        short8 til = read_frag(TpU + 3 * PLSZ, n, k);
        short8 urh = read_frag(Up + 0 * PLSZ, n, k);
        short8 uih = read_frag(Up + 1 * PLSZ, n, k);
        short8 url = read_frag(Up + 2 * PLSZ, n, k);
        short8 uil = read_frag(Up + 3 * PLSZ, n, k);
        #pragma unroll
        for (int s = 0; s < 2; ++s) {
            int m = w * 32 + s * 16 + m15;
            short8 Ac[6], Ad[6];
            #pragma unroll
            for (int pl = 0; pl < 6; ++pl) { Ac[pl] = aread(W2, pl, m, k); Ad[pl] = aread(W3, pl, m, k); }
            cmfma12(Ac, trh, tih, trl, til, aR[s], aI[s]);
            cmfma12(Ad, urh, uih, url, uil, aR[s], aI[s]);
        }
    }

    // ---- write W back to Uhat (block-disjoint tiles) ----
    #pragma unroll
    for (int s = 0; s < 2; ++s) {
        int n = m15;
        if (n < ncols) {
            #pragma unroll
            for (int reg = 0; reg < 4; ++reg) {
                int m = w * 32 + s * 16 + quad * 4 + reg;
                Uhat[(size_t)(b * 128 + m) * LF + l0 + n] = make_float2(aR[s][reg], aI[s][reg]);
            }
        }
    }
}

// ---------------------------------------------------------------------------
extern "C" void kernel_launch(void* const* d_in, const int* in_sizes, int n_in,
                              void* d_out, int out_size, void* d_ws, size_t ws_size,
                              hipStream_t stream) {
    const float* u    = (const float*)d_in[0];   // (B,H,L)
    const float* C_ri = (const float*)d_in[1];   // (H,P,2)
    const float* D_ri = (const float*)d_in[2];   // (H,H,2)
    const float* B_ri = (const float*)d_in[3];   // (P,H,2)
    const float* Lam  = (const float*)d_in[4];   // (P,2)
    float* out = (float*)d_out;

    float2* Uhat = (float2*)d_ws;                          // 1024*2049 float2 = 16 MiB
    unsigned short* W1 = (unsigned short*)(Uhat + (size_t)NROWS * LF);
    unsigned short* W2 = W1 + 6 * WPLSZ;
    unsigned short* W3 = W2 + 6 * WPLSZ;
    float2* Em = (float2*)(W3 + 6 * WPLSZ);

    prep_ABE_k<<<192, 256, 0, stream>>>(B_ri, C_ri, D_ri, W1, W2, Em);
    prep_W3_k<<<64, 256, 0, stream>>>(Em, W3);

    rfft_rows_k<<<NROWS, 256, 0, stream>>>(u, Uhat);
    mixmm_k<<<Bn * NTILES, 256, 0, stream>>>(Uhat, W1, W2, W3, Lam);
    irfft_gelu_k<<<NROWS, 256, 0, stream>>>(Uhat, out);
}

// Round 5
// 212.749 us; speedup vs baseline: 1.0315x; 1.0315x over previous
//
#include <hip/hip_runtime.h>
#include <math.h>

#define Bn 8
#define Hn 128
#define Pn 128
#define Ln 4096
#define LF 2049           // Ln/2 + 1
#define NROWS (Bn*Hn)     // 1024
#define NT 16             // frequency columns per mixmm block
#define NTILES 129        // ceil(2049/16) per batch
#define PLSZ 2048         // ushorts per data plane (16 x 128)
#define WPLSZ 16384       // ushorts per weight plane (128 x 128)

// LDS skew for FFT buffers: +1 float2 every 16 -> strided Stockham writes <=2-way
#define SKEW(a) ((a) + ((a) >> 4))
#define FBUF 2176          // SKEW(2047)+1 rounded up

typedef __attribute__((ext_vector_type(8))) short short8;
typedef __attribute__((ext_vector_type(4))) float f32x4;

// ---------------------------------------------------------------------------
// bf16 helpers
// ---------------------------------------------------------------------------
__device__ __forceinline__ unsigned short bf16_rne(float x) {
    unsigned u = __float_as_uint(x);
    unsigned r = u + 0x7FFFu + ((u >> 16) & 1u);
    return (unsigned short)(r >> 16);
}
__device__ __forceinline__ void bf16_split(float x, unsigned short& hi, unsigned short& lo) {
    hi = bf16_rne(x);
    float fhi = __uint_as_float(((unsigned)hi) << 16);
    lo = bf16_rne(x - fhi);
}

// ---------------------------------------------------------------------------
// prep: fold H-axis FFTs into weights; bf16 hi/lo planes, [m][k] row-major.
// Planes: 0 r_hi, 1 i_hi, 2 (-i)_hi, 3 r_lo, 4 i_lo, 5 (-i)_lo
//   W1[p][h] = (B_bar @ F)[p][h]
//   W2[h][p] = (Finv @ C)[h][p]
//   E [a][q] = (D @ F)[a][q]  (fp32 temp)
//   W3[h][q] = (Finv @ E)[h][q]
// ---------------------------------------------------------------------------
__device__ __forceinline__ void write6(unsigned short* __restrict__ W, int idx,
                                       float vr, float vi) {
    unsigned short rh, rl, ih, il, nh, nl;
    bf16_split(vr, rh, rl);
    bf16_split(vi, ih, il);
    bf16_split(-vi, nh, nl);
    W[0 * WPLSZ + idx] = rh;
    W[1 * WPLSZ + idx] = ih;
    W[2 * WPLSZ + idx] = nh;
    W[3 * WPLSZ + idx] = rl;
    W[4 * WPLSZ + idx] = il;
    W[5 * WPLSZ + idx] = nl;
}

__global__ void prep_ABE_k(const float* __restrict__ B_ri, const float* __restrict__ C_ri,
                           const float* __restrict__ D_ri,
                           unsigned short* __restrict__ W1, unsigned short* __restrict__ W2,
                           float2* __restrict__ E) {
    int bid = blockIdx.x;
    int idx = (bid & 63) * 256 + threadIdx.x;   // 0..16383
    int rrow = idx >> 7, ccol = idx & 127;
    if (bid < 64) {
        // W1[p][h], p=rrow h=ccol
        float sr = 0.f, si = 0.f;
        for (int q = 0; q < 128; ++q) {
            float br = B_ri[(rrow * 128 + q) * 2 + 0];
            float bi = B_ri[(rrow * 128 + q) * 2 + 1];
            float ang = -3.14159265358979f * (float)((q * ccol) & 127) / 64.0f;
            float sw, cw; __sincosf(ang, &sw, &cw);
            sr += br * cw - bi * sw;
            si += br * sw + bi * cw;
        }
        write6(W1, idx, sr, si);
    } else if (bid < 128) {
        // W2[h][p], h=rrow p=ccol
        float sr = 0.f, si = 0.f;
        for (int h2 = 0; h2 < 128; ++h2) {
            float cr = C_ri[(h2 * 128 + ccol) * 2 + 0];
            float ci = C_ri[(h2 * 128 + ccol) * 2 + 1];
            float ang = 3.14159265358979f * (float)((rrow * h2) & 127) / 64.0f;
            float sw, cw; __sincosf(ang, &sw, &cw);
            sr += cr * cw - ci * sw;
            si += cr * sw + ci * cw;
        }
        write6(W2, idx, sr * (1.0f / 128.0f), si * (1.0f / 128.0f));
    } else {
        // E[a][q], a=rrow q=ccol
        float sr = 0.f, si = 0.f;
        for (int c = 0; c < 128; ++c) {
            float dr = D_ri[(rrow * 128 + c) * 2 + 0];
            float di = D_ri[(rrow * 128 + c) * 2 + 1];
            float ang = -3.14159265358979f * (float)((c * ccol) & 127) / 64.0f;
            float sw, cw; __sincosf(ang, &sw, &cw);
            sr += dr * cw - di * sw;
            si += dr * sw + di * cw;
        }
        E[idx] = make_float2(sr, si);
    }
}

__global__ void prep_W3_k(const float2* __restrict__ E, unsigned short* __restrict__ W3) {
    int idx = blockIdx.x * blockDim.x + threadIdx.x;   // h*128 + q
    int h = idx >> 7, q = idx & 127;
    float sr = 0.f, si = 0.f;
    for (int a = 0; a < 128; ++a) {
        float2 e = E[a * 128 + q];
        float ang = 3.14159265358979f * (float)((h * a) & 127) / 64.0f;
        float sw, cw; __sincosf(ang, &sw, &cw);
        sr += e.x * cw - e.y * sw;
        si += e.x * sw + e.y * cw;
    }
    write6(W3, idx, sr * (1.0f / 128.0f), si * (1.0f / 128.0f));
}

// ---------------------------------------------------------------------------
// 2048-pt Stockham FFT in LDS: radix-8 x3 + radix-4 (final, twiddle-free).
//   dst[q+(Rp+j)s] = (sum_u src[q+(p+um)s] w_R^{SIGN ju}) * e^{SIGN 2pi i j p s/N}
// Twiddles computed EXACTLY per j via __sincosf(j*ang) — the w^j recurrence
// cost absmax 4->12 in round 4; per-j sincos is ~0.6 us total across both
// FFT kernels (172k wave-level transcendental issues), noise.
// Reads contiguous: src[k + u*N/R]. All addresses SKEWed. 256 threads.
// ---------------------------------------------------------------------------
__device__ __forceinline__ float2 cadd2(float2 a, float2 b) { return make_float2(a.x + b.x, a.y + b.y); }
__device__ __forceinline__ float2 csub2(float2 a, float2 b) { return make_float2(a.x - b.x, a.y - b.y); }

template <int SIGN>
__device__ __forceinline__ void dft4(float2 a0, float2 a1, float2 a2, float2 a3,
                                     float2& y0, float2& y1, float2& y2, float2& y3) {
    float t0x = a0.x + a2.x, t0y = a0.y + a2.y;
    float t1x = a0.x - a2.x, t1y = a0.y - a2.y;
    float t2x = a1.x + a3.x, t2y = a1.y + a3.y;
    float t3x = a1.x - a3.x, t3y = a1.y - a3.y;
    y0 = make_float2(t0x + t2x, t0y + t2y);
    y2 = make_float2(t0x - t2x, t0y - t2y);
    y1 = make_float2(t1x - (float)SIGN * t3y, t1y + (float)SIGN * t3x);
    y3 = make_float2(t1x + (float)SIGN * t3y, t1y - (float)SIGN * t3x);
}

template <int SIGN>
__device__ __forceinline__ void fft2048(float2* bufA, float2* bufB) {
    const int tid = threadIdx.x;
    float2* src = bufA;
    float2* dst = bufB;
    #pragma unroll
    for (int stg = 0; stg < 3; ++stg) {
        const int ls = 3 * stg;           // s = 8^stg
        const int k = tid;                // 256 butterflies
        const int q = k & ((1 << ls) - 1);
        const int p = k >> ls;
        float2 a[8];
        #pragma unroll
        for (int u = 0; u < 8; ++u) a[u] = src[SKEW(k + (u << 8))];
        float2 A0, A1, A2, A3, B0, B1, B2, B3;
        dft4<SIGN>(a[0], a[2], a[4], a[6], A0, A1, A2, A3);
        dft4<SIGN>(a[1], a[3], a[5], a[7], B0, B1, B2, B3);
        const float c45 = 0.70710678118655f;
        float2 w1 = make_float2(c45 * (B1.x - (float)SIGN * B1.y), c45 * ((float)SIGN * B1.x + B1.y));
        float2 w2 = make_float2(-(float)SIGN * B2.y, (float)SIGN * B2.x);
        float2 w3 = make_float2(c45 * (-B3.x - (float)SIGN * B3.y), c45 * ((float)SIGN * B3.x - B3.y));
        float2 b[8];
        b[0] = cadd2(A0, B0);  b[4] = csub2(A0, B0);
        b[1] = cadd2(A1, w1);  b[5] = csub2(A1, w1);
        b[2] = cadd2(A2, w2);  b[6] = csub2(A2, w2);
        b[3] = cadd2(A3, w3);  b[7] = csub2(A3, w3);
        float ang = (float)SIGN * 6.28318530717959f * (float)p * (1.0f / (float)(2048 >> ls));
        #pragma unroll
        for (int j = 1; j < 8; ++j) {
            float sj, cj; __sincosf((float)j * ang, &sj, &cj);
            b[j] = make_float2(b[j].x * cj - b[j].y * sj, b[j].x * sj + b[j].y * cj);
        }
        const int base = q + (p << (ls + 3));
        #pragma unroll
        for (int j = 0; j < 8; ++j) dst[SKEW(base + (j << ls))] = b[j];
        __syncthreads();
        float2* t = src; src = dst; dst = t;
    }
    // final radix-4: s=512, m=1 -> p=0, twiddles = 1
    #pragma unroll
    for (int r = 0; r < 2; ++r) {
        int k = tid + (r << 8);
        float2 a0 = src[SKEW(k)];
        float2 a1 = src[SKEW(k + 512)];
        float2 a2 = src[SKEW(k + 1024)];
        float2 a3 = src[SKEW(k + 1536)];
        float2 y0, y1, y2, y3;
        dft4<SIGN>(a0, a1, a2, a3, y0, y1, y2, y3);
        dst[SKEW(k)] = y0;
        dst[SKEW(k + 512)] = y1;
        dst[SKEW(k + 1024)] = y2;
        dst[SKEW(k + 1536)] = y3;
    }
    __syncthreads();
    // stages: A->B, B->A, A->B, B->A  => result in bufA
}

// rfft via real-packing: z[n] = u[2n] + i u[2n+1]; U from Z by even/odd unpack.
__global__ __launch_bounds__(256, 4) void rfft_rows_k(const float* __restrict__ u,
                                                      float2* __restrict__ Uhat) {
    __shared__ __align__(16) float2 bufA[FBUF];
    __shared__ __align__(16) float2 bufB[FBUF];
    const int row = blockIdx.x;
    const int tid = threadIdx.x;
    const float2* up = (const float2*)(u + (size_t)row * Ln);
    for (int i = tid; i < 2048; i += 256) bufA[SKEW(i)] = up[i];
    __syncthreads();
    fft2048<-1>(bufA, bufB);
    float2* op = Uhat + (size_t)row * LF;
    for (int l = tid; l < 1025; l += 256) {
        float2 Zl = bufA[SKEW(l)];
        float2 Zm = bufA[SKEW((2048 - l) & 2047)];
        float2 Fe = make_float2(0.5f * (Zl.x + Zm.x), 0.5f * (Zl.y - Zm.y));
        float2 Dv = make_float2(0.5f * (Zl.x - Zm.x), 0.5f * (Zl.y + Zm.y));
        float2 Fo = make_float2(Dv.y, -Dv.x);                 // Dv / i
        float s, c; __sincosf(-3.14159265358979f * (float)l / 2048.0f, &s, &c);
        float2 TF = make_float2(Fo.x * c - Fo.y * s, Fo.x * s + Fo.y * c);
        op[l] = make_float2(Fe.x + TF.x, Fe.y + TF.y);
        op[2048 - l] = make_float2(Fe.x - TF.x, -(Fe.y - TF.y));   // conj(Fe - TF)
    }
}

// irfft via inverse packing: Z[l] = Fe + i Fo rebuilt from U, then 2048 IFFT,
// y[2n]=Re(z), y[2n+1]=Im(z), scale 1/2048, exact GELU.
__global__ __launch_bounds__(256, 4) void irfft_gelu_k(const float2* __restrict__ Uhat,
                                                       float* __restrict__ out) {
    __shared__ __align__(16) float2 bufA[FBUF];
    __shared__ __align__(16) float2 bufB[FBUF];
    const int row = blockIdx.x;
    const int tid = threadIdx.x;
    const float2* wp = Uhat + (size_t)row * LF;
    for (int l = tid; l < 1025; l += 256) {
        float2 Ul = wp[l];
        float2 Um = wp[2048 - l];
        float2 Fe = make_float2(0.5f * (Ul.x + Um.x), 0.5f * (Ul.y - Um.y));
        float2 Dv = make_float2(0.5f * (Ul.x - Um.x), 0.5f * (Ul.y + Um.y));
        float s, c; __sincosf(3.14159265358979f * (float)l / 2048.0f, &s, &c);
        float2 Fo = make_float2(Dv.x * c - Dv.y * s, Dv.x * s + Dv.y * c);
        bufA[SKEW(l)] = make_float2(Fe.x - Fo.y, Fe.y + Fo.x);          // Fe + i Fo
        if (l >= 1 && l <= 1023)
            bufA[SKEW(2048 - l)] = make_float2(Fe.x + Fo.y, Fo.x - Fe.y); // conj(Fe)+i conj(Fo)
    }
    __syncthreads();
    fft2048<1>(bufA, bufB);
    float2* op = (float2*)(out + (size_t)row * Ln);
    for (int n = tid; n < 2048; n += 256) {
        float2 z = bufA[SKEW(n)];
        float y0 = z.x * (1.0f / 2048.0f);
        float y1 = z.y * (1.0f / 2048.0f);
        op[n] = make_float2(0.5f * y0 * (1.0f + erff(y0 * 0.70710678118655f)),
                            0.5f * y1 * (1.0f + erff(y1 * 0.70710678118655f)));
    }
}

// ---------------------------------------------------------------------------
// mixmm: NT=16 frequency columns per block, one batch each; 32 KB LDS.
// __launch_bounds__(256,4): VGPR cap 128 — round 4's (256,5) squeezed VGPRs
// to 48 and spilled 44 MB to scratch (WRITE_SIZE 18->62 MB, MfmaUtil 10->7%).
// 4 blocks/CU = 16 waves, no spill.
//   T = B2 @ U ; T *= mid(p,l) ; W = C2 @ T + D2 @ U
// bf16 3-term hi/lo split; MFMA 16x16x32 bf16 (layouts verified r3).
// ---------------------------------------------------------------------------
__device__ __forceinline__ f32x4 mfma16(short8 a, short8 b, f32x4 c) {
    return __builtin_amdgcn_mfma_f32_16x16x32_bf16(a, b, c, 0, 0, 0);
}
__device__ __forceinline__ short8 read_frag(const unsigned short* plane, int n, int k) {
    int ksw = k ^ ((n & 7) << 3);
    return *(const short8*)(plane + n * 128 + ksw);
}
__device__ __forceinline__ short8 aread(const unsigned short* W, int pl, int m, int k) {
    return *(const short8*)(W + pl * WPLSZ + m * 128 + k);
}
__device__ __forceinline__ void cmfma12(const short8 A[6],
                                        short8 brh, short8 bih, short8 brl, short8 bil,
                                        f32x4& aR, f32x4& aI) {
    aR = mfma16(A[0], brh, aR);  aR = mfma16(A[2], bih, aR);   // hi*hi
    aR = mfma16(A[3], brh, aR);  aR = mfma16(A[5], bih, aR);   // lo*hi
    aR = mfma16(A[0], brl, aR);  aR = mfma16(A[2], bil, aR);   // hi*lo
    aI = mfma16(A[0], bih, aI);  aI = mfma16(A[1], brh, aI);
    aI = mfma16(A[3], bih, aI);  aI = mfma16(A[4], brh, aI);
    aI = mfma16(A[0], bil, aI);  aI = mfma16(A[1], brl, aI);
}

__global__ __launch_bounds__(256, 4) void mixmm_k(float2* __restrict__ Uhat,
                                                  const unsigned short* __restrict__ W1,
                                                  const unsigned short* __restrict__ W2,
                                                  const unsigned short* __restrict__ W3,
                                                  const float* __restrict__ Lam) {
    // data planes: 0 r_hi, 1 i_hi, 2 r_lo, 3 i_lo
    __shared__ __align__(16) unsigned short Up[4 * PLSZ];    // 16 KB
    __shared__ __align__(16) unsigned short TpU[4 * PLSZ];   // 16 KB (T planes / U fp32 stage)
    float2* Ustage = (float2*)TpU;                           // [128][16] overlay

    const int tid = threadIdx.x;
    const int b = blockIdx.x / NTILES;
    const int tile = blockIdx.x % NTILES;
    const int l0 = tile * NT;
    const int ncols = (LF - l0) < NT ? (LF - l0) : NT;

    // ---- load U tile ----
    for (int i = tid; i < 128 * NT; i += 256) {
        int h = i >> 4, n = i & 15;
        float2 v = make_float2(0.f, 0.f);
        if (n < ncols) v = Uhat[(size_t)(b * 128 + h) * LF + l0 + n];
        Ustage[h * NT + n] = v;
    }
    __syncthreads();

    // ---- convert to bf16 hi/lo planes [n][k=h], swizzled ----
    {
        int n = tid & 15, kc = tid >> 4;   // kc 0..15: h = kc*8 + j
        short8 rh, ih, rl, il;
        #pragma unroll
        for (int j = 0; j < 8; ++j) {
            int h = kc * 8 + j;
            float2 v = Ustage[h * NT + n];
            unsigned short a, bb, c, d;
            bf16_split(v.x, a, bb);
            bf16_split(v.y, c, d);
            rh[j] = (short)a; rl[j] = (short)bb;
            ih[j] = (short)c; il[j] = (short)d;
        }
        int k0 = kc * 8;
        int ksw = k0 ^ ((n & 7) << 3);
        *(short8*)(Up + 0 * PLSZ + n * 128 + ksw) = rh;
        *(short8*)(Up + 1 * PLSZ + n * 128 + ksw) = ih;
        *(short8*)(Up + 2 * PLSZ + n * 128 + ksw) = rl;
        *(short8*)(Up + 3 * PLSZ + n * 128 + ksw) = il;
    }
    __syncthreads();   // Up ready; Ustage consumed (TpU free for T planes)

    const int lane = tid & 63;
    const int w = tid >> 6;          // wave: rows w*32 .. w*32+31
    const int m15 = lane & 15;
    const int quad = lane >> 4;

    f32x4 aR[2], aI[2];
    #pragma unroll
    for (int s = 0; s < 2; ++s) { aR[s] = (f32x4)0.f; aI[s] = (f32x4)0.f; }

    // ---- stage 1: T = B2 @ U ----
    for (int kb = 0; kb < 4; ++kb) {
        int k = kb * 32 + quad * 8;
        int n = m15;
        short8 brh = read_frag(Up + 0 * PLSZ, n, k);
        short8 bih = read_frag(Up + 1 * PLSZ, n, k);
        short8 brl = read_frag(Up + 2 * PLSZ, n, k);
        short8 bil = read_frag(Up + 3 * PLSZ, n, k);
        #pragma unroll
        for (int s = 0; s < 2; ++s) {
            int m = w * 32 + s * 16 + m15;
            short8 A[6];
            #pragma unroll
            for (int pl = 0; pl < 6; ++pl) A[pl] = aread(W1, pl, m, k);
            cmfma12(A, brh, bih, brl, bil, aR[s], aI[s]);
        }
    }

    // ---- Cauchy scale + write T planes ----
    #pragma unroll
    for (int s = 0; s < 2; ++s) {
        #pragma unroll
        for (int reg = 0; reg < 4; ++reg) {
            int p = w * 32 + s * 16 + quad * 4 + reg;
            float2 lamv = ((const float2*)Lam)[p];
            float dr = -lamv.x;
            int n = m15;
            int l = l0 + n;
            float di = 3.14159265358979f * (float)l / 2048.0f - lamv.y;
            float inv = 1.0f / (dr * dr + di * di);
            float xr = aR[s][reg], xi = aI[s][reg];
            float tr = (xr * dr + xi * di) * inv;
            float ti = (xi * dr - xr * di) * inv;
            unsigned short trh, trl, tih, til;
            bf16_split(tr, trh, trl);
            bf16_split(ti, tih, til);
            int off = n * 128 + (p ^ ((n & 7) << 3));
            TpU[0 * PLSZ + off] = trh;
            TpU[1 * PLSZ + off] = tih;
            TpU[2 * PLSZ + off] = trl;
            TpU[3 * PLSZ + off] = til;
        }
    }
    __syncthreads();   // T planes visible

    // ---- stage 2: W = C2 @ T + D2 @ U ----
    #pragma unroll
    for (int s = 0; s < 2; ++s) { aR[s] = (f32x4)0.f; aI[s] = (f32x4)0.f; }

    for (int kb = 0; kb < 4; ++kb) {
        int k = kb * 32 + quad * 8;
        int n = m15;
        short8 trh = read_frag(TpU + 0 * PLSZ, n, k);
        short8 tih = read_frag(TpU + 1 * PLSZ, n, k);
        short8 trl = read_frag(TpU + 2 * PLSZ, n, k);
        short8 til = read_frag(TpU + 3 * PLSZ, n, k);
        short8 urh = read_frag(Up + 0 * PLSZ, n, k);
        short8 uih = read_frag(Up + 1 * PLSZ, n, k);
        short8 url = read_frag(Up + 2 * PLSZ, n, k);
        short8 uil = read_frag(Up + 3 * PLSZ, n, k);
        #pragma unroll
        for (int s = 0; s < 2; ++s) {
            int m = w * 32 + s * 16 + m15;
            short8 Ac[6], Ad[6];
            #pragma unroll
            for (int pl = 0; pl < 6; ++pl) { Ac[pl] = aread(W2, pl, m, k); Ad[pl] = aread(W3, pl, m, k); }
            cmfma12(Ac, trh, tih, trl, til, aR[s], aI[s]);
            cmfma12(Ad, urh, uih, url, uil, aR[s], aI[s]);
        }
    }

    // ---- write W back to Uhat (block-disjoint tiles) ----
    #pragma unroll
    for (int s = 0; s < 2; ++s) {
        int n = m15;
        if (n < ncols) {
            #pragma unroll
            for (int reg = 0; reg < 4; ++reg) {
                int m = w * 32 + s * 16 + quad * 4 + reg;
                Uhat[(size_t)(b * 128 + m) * LF + l0 + n] = make_float2(aR[s][reg], aI[s][reg]);
            }
        }
    }
}

// ---------------------------------------------------------------------------
extern "C" void kernel_launch(void* const* d_in, const int* in_sizes, int n_in,
                              void* d_out, int out_size, void* d_ws, size_t ws_size,
                              hipStream_t stream) {
    const float* u    = (const float*)d_in[0];   // (B,H,L)
    const float* C_ri = (const float*)d_in[1];   // (H,P,2)
    const float* D_ri = (const float*)d_in[2];   // (H,H,2)
    const float* B_ri = (const float*)d_in[3];   // (P,H,2)
    const float* Lam  = (const float*)d_in[4];   // (P,2)
    float* out = (float*)d_out;

    float2* Uhat = (float2*)d_ws;                          // 1024*2049 float2 = 16 MiB
    unsigned short* W1 = (unsigned short*)(Uhat + (size_t)NROWS * LF);
    unsigned short* W2 = W1 + 6 * WPLSZ;
    unsigned short* W3 = W2 + 6 * WPLSZ;
    float2* Em = (float2*)(W3 + 6 * WPLSZ);

    prep_ABE_k<<<192, 256, 0, stream>>>(B_ri, C_ri, D_ri, W1, W2, Em);
    prep_W3_k<<<64, 256, 0, stream>>>(Em, W3);

    rfft_rows_k<<<NROWS, 256, 0, stream>>>(u, Uhat);
    mixmm_k<<<Bn * NTILES, 256, 0, stream>>>(Uhat, W1, W2, W3, Lam);
    irfft_gelu_k<<<NROWS, 256, 0, stream>>>(Uhat, out);
}

// Round 6
// 171.861 us; speedup vs baseline: 1.2769x; 1.2379x over previous
//
#include <hip/hip_runtime.h>
#include <math.h>

#define Bn 8
#define Hn 128
#define Pn 128
#define Ln 4096
#define LF 2049           // Ln/2 + 1
#define NROWS (Bn*Hn)     // 1024
#define NT 16             // frequency columns per mixmm block
#define NTILES 129        // ceil(2049/16) per batch
#define PLSZ 2048         // halfs per data plane (16 x 128)
#define WPLSZ 16384       // halfs per weight plane (128 x 128)
#define TSCALE 64.0f      // T stored as T/64 (fp16 range guard); W2 pre-scaled x64

// LDS skew for FFT buffers: +1 float2 every 16 -> strided Stockham writes <=2-way
#define SKEW(a) ((a) + ((a) >> 4))
#define FBUF 2176          // SKEW(2047)+1 rounded up

typedef _Float16 f16x8 __attribute__((ext_vector_type(8)));
typedef float f32x4 __attribute__((ext_vector_type(4)));

// ---------------------------------------------------------------------------
// prep: fold H-axis FFTs into weights; fp16 planes {0:r, 1:i, 2:-i},
// [m][k] row-major 128x128.
//   W1[p][h] = (B_bar @ F)[p][h]               (stage 1: T = B2 @ U)
//   W2[h][p] = (Finv @ C)[h][p] * TSCALE       (stage 2: C2 @ T, T stored /64)
//   E [a][q] = (D @ F)[a][q]  (fp32 temp)
//   W3[h][q] = (Finv @ E)[h][q]                (stage 2: D2 @ U)
// ---------------------------------------------------------------------------
__device__ __forceinline__ void write3(_Float16* __restrict__ W, int idx,
                                       float vr, float vi) {
    W[0 * WPLSZ + idx] = (_Float16)vr;
    W[1 * WPLSZ + idx] = (_Float16)vi;
    W[2 * WPLSZ + idx] = (_Float16)(-vi);
}

__global__ void prep_ABE_k(const float* __restrict__ B_ri, const float* __restrict__ C_ri,
                           const float* __restrict__ D_ri,
                           _Float16* __restrict__ W1, _Float16* __restrict__ W2,
                           float2* __restrict__ E) {
    int bid = blockIdx.x;
    int idx = (bid & 63) * 256 + threadIdx.x;   // 0..16383
    int rrow = idx >> 7, ccol = idx & 127;
    if (bid < 64) {
        // W1[p][h], p=rrow h=ccol
        float sr = 0.f, si = 0.f;
        for (int q = 0; q < 128; ++q) {
            float br = B_ri[(rrow * 128 + q) * 2 + 0];
            float bi = B_ri[(rrow * 128 + q) * 2 + 1];
            float ang = -3.14159265358979f * (float)((q * ccol) & 127) / 64.0f;
            float sw, cw; __sincosf(ang, &sw, &cw);
            sr += br * cw - bi * sw;
            si += br * sw + bi * cw;
        }
        write3(W1, idx, sr, si);
    } else if (bid < 128) {
        // W2[h][p], h=rrow p=ccol; x TSCALE/128
        float sr = 0.f, si = 0.f;
        for (int h2 = 0; h2 < 128; ++h2) {
            float cr = C_ri[(h2 * 128 + ccol) * 2 + 0];
            float ci = C_ri[(h2 * 128 + ccol) * 2 + 1];
            float ang = 3.14159265358979f * (float)((rrow * h2) & 127) / 64.0f;
            float sw, cw; __sincosf(ang, &sw, &cw);
            sr += cr * cw - ci * sw;
            si += cr * sw + ci * cw;
        }
        write3(W2, idx, sr * (TSCALE / 128.0f), si * (TSCALE / 128.0f));
    } else {
        // E[a][q], a=rrow q=ccol
        float sr = 0.f, si = 0.f;
        for (int c = 0; c < 128; ++c) {
            float dr = D_ri[(rrow * 128 + c) * 2 + 0];
            float di = D_ri[(rrow * 128 + c) * 2 + 1];
            float ang = -3.14159265358979f * (float)((c * ccol) & 127) / 64.0f;
            float sw, cw; __sincosf(ang, &sw, &cw);
            sr += dr * cw - di * sw;
            si += dr * sw + di * cw;
        }
        E[idx] = make_float2(sr, si);
    }
}

__global__ void prep_W3_k(const float2* __restrict__ E, _Float16* __restrict__ W3) {
    int idx = blockIdx.x * blockDim.x + threadIdx.x;   // h*128 + q
    int h = idx >> 7, q = idx & 127;
    float sr = 0.f, si = 0.f;
    for (int a = 0; a < 128; ++a) {
        float2 e = E[a * 128 + q];
        float ang = 3.14159265358979f * (float)((h * a) & 127) / 64.0f;
        float sw, cw; __sincosf(ang, &sw, &cw);
        sr += e.x * cw - e.y * sw;
        si += e.x * sw + e.y * cw;
    }
    write3(W3, idx, sr * (1.0f / 128.0f), si * (1.0f / 128.0f));
}

// ---------------------------------------------------------------------------
// 2048-pt Stockham FFT in LDS: radix-8 x3 + radix-4 (final, twiddle-free).
// (unchanged from round 5)
// ---------------------------------------------------------------------------
__device__ __forceinline__ float2 cadd2(float2 a, float2 b) { return make_float2(a.x + b.x, a.y + b.y); }
__device__ __forceinline__ float2 csub2(float2 a, float2 b) { return make_float2(a.x - b.x, a.y - b.y); }

template <int SIGN>
__device__ __forceinline__ void dft4(float2 a0, float2 a1, float2 a2, float2 a3,
                                     float2& y0, float2& y1, float2& y2, float2& y3) {
    float t0x = a0.x + a2.x, t0y = a0.y + a2.y;
    float t1x = a0.x - a2.x, t1y = a0.y - a2.y;
    float t2x = a1.x + a3.x, t2y = a1.y + a3.y;
    float t3x = a1.x - a3.x, t3y = a1.y - a3.y;
    y0 = make_float2(t0x + t2x, t0y + t2y);
    y2 = make_float2(t0x - t2x, t0y - t2y);
    y1 = make_float2(t1x - (float)SIGN * t3y, t1y + (float)SIGN * t3x);
    y3 = make_float2(t1x + (float)SIGN * t3y, t1y - (float)SIGN * t3x);
}

template <int SIGN>
__device__ __forceinline__ void fft2048(float2* bufA, float2* bufB) {
    const int tid = threadIdx.x;
    float2* src = bufA;
    float2* dst = bufB;
    #pragma unroll
    for (int stg = 0; stg < 3; ++stg) {
        const int ls = 3 * stg;           // s = 8^stg
        const int k = tid;                // 256 butterflies
        const int q = k & ((1 << ls) - 1);
        const int p = k >> ls;
        float2 a[8];
        #pragma unroll
        for (int u = 0; u < 8; ++u) a[u] = src[SKEW(k + (u << 8))];
        float2 A0, A1, A2, A3, B0, B1, B2, B3;
        dft4<SIGN>(a[0], a[2], a[4], a[6], A0, A1, A2, A3);
        dft4<SIGN>(a[1], a[3], a[5], a[7], B0, B1, B2, B3);
        const float c45 = 0.70710678118655f;
        float2 w1 = make_float2(c45 * (B1.x - (float)SIGN * B1.y), c45 * ((float)SIGN * B1.x + B1.y));
        float2 w2 = make_float2(-(float)SIGN * B2.y, (float)SIGN * B2.x);
        float2 w3 = make_float2(c45 * (-B3.x - (float)SIGN * B3.y), c45 * ((float)SIGN * B3.x - B3.y));
        float2 b[8];
        b[0] = cadd2(A0, B0);  b[4] = csub2(A0, B0);
        b[1] = cadd2(A1, w1);  b[5] = csub2(A1, w1);
        b[2] = cadd2(A2, w2);  b[6] = csub2(A2, w2);
        b[3] = cadd2(A3, w3);  b[7] = csub2(A3, w3);
        float ang = (float)SIGN * 6.28318530717959f * (float)p * (1.0f / (float)(2048 >> ls));
        #pragma unroll
        for (int j = 1; j < 8; ++j) {
            float sj, cj; __sincosf((float)j * ang, &sj, &cj);
            b[j] = make_float2(b[j].x * cj - b[j].y * sj, b[j].x * sj + b[j].y * cj);
        }
        const int base = q + (p << (ls + 3));
        #pragma unroll
        for (int j = 0; j < 8; ++j) dst[SKEW(base + (j << ls))] = b[j];
        __syncthreads();
        float2* t = src; src = dst; dst = t;
    }
    // final radix-4: s=512, m=1 -> p=0, twiddles = 1
    #pragma unroll
    for (int r = 0; r < 2; ++r) {
        int k = tid + (r << 8);
        float2 a0 = src[SKEW(k)];
        float2 a1 = src[SKEW(k + 512)];
        float2 a2 = src[SKEW(k + 1024)];
        float2 a3 = src[SKEW(k + 1536)];
        float2 y0, y1, y2, y3;
        dft4<SIGN>(a0, a1, a2, a3, y0, y1, y2, y3);
        dst[SKEW(k)] = y0;
        dst[SKEW(k + 512)] = y1;
        dst[SKEW(k + 1024)] = y2;
        dst[SKEW(k + 1536)] = y3;
    }
    __syncthreads();
    // stages: A->B, B->A, A->B, B->A  => result in bufA
}

// rfft via real-packing: z[n] = u[2n] + i u[2n+1]; U from Z by even/odd unpack.
__global__ __launch_bounds__(256, 4) void rfft_rows_k(const float* __restrict__ u,
                                                      float2* __restrict__ Uhat) {
    __shared__ __align__(16) float2 bufA[FBUF];
    __shared__ __align__(16) float2 bufB[FBUF];
    const int row = blockIdx.x;
    const int tid = threadIdx.x;
    const float2* up = (const float2*)(u + (size_t)row * Ln);
    for (int i = tid; i < 2048; i += 256) bufA[SKEW(i)] = up[i];
    __syncthreads();
    fft2048<-1>(bufA, bufB);
    float2* op = Uhat + (size_t)row * LF;
    for (int l = tid; l < 1025; l += 256) {
        float2 Zl = bufA[SKEW(l)];
        float2 Zm = bufA[SKEW((2048 - l) & 2047)];
        float2 Fe = make_float2(0.5f * (Zl.x + Zm.x), 0.5f * (Zl.y - Zm.y));
        float2 Dv = make_float2(0.5f * (Zl.x - Zm.x), 0.5f * (Zl.y + Zm.y));
        float2 Fo = make_float2(Dv.y, -Dv.x);                 // Dv / i
        float s, c; __sincosf(-3.14159265358979f * (float)l / 2048.0f, &s, &c);
        float2 TF = make_float2(Fo.x * c - Fo.y * s, Fo.x * s + Fo.y * c);
        op[l] = make_float2(Fe.x + TF.x, Fe.y + TF.y);
        op[2048 - l] = make_float2(Fe.x - TF.x, -(Fe.y - TF.y));   // conj(Fe - TF)
    }
}

// irfft via inverse packing: Z[l] = Fe + i Fo rebuilt from U, then 2048 IFFT,
// y[2n]=Re(z), y[2n+1]=Im(z), scale 1/2048, exact GELU.
__global__ __launch_bounds__(256, 4) void irfft_gelu_k(const float2* __restrict__ Uhat,
                                                       float* __restrict__ out) {
    __shared__ __align__(16) float2 bufA[FBUF];
    __shared__ __align__(16) float2 bufB[FBUF];
    const int row = blockIdx.x;
    const int tid = threadIdx.x;
    const float2* wp = Uhat + (size_t)row * LF;
    for (int l = tid; l < 1025; l += 256) {
        float2 Ul = wp[l];
        float2 Um = wp[2048 - l];
        float2 Fe = make_float2(0.5f * (Ul.x + Um.x), 0.5f * (Ul.y - Um.y));
        float2 Dv = make_float2(0.5f * (Ul.x - Um.x), 0.5f * (Ul.y + Um.y));
        float s, c; __sincosf(3.14159265358979f * (float)l / 2048.0f, &s, &c);
        float2 Fo = make_float2(Dv.x * c - Dv.y * s, Dv.x * s + Dv.y * c);
        bufA[SKEW(l)] = make_float2(Fe.x - Fo.y, Fe.y + Fo.x);          // Fe + i Fo
        if (l >= 1 && l <= 1023)
            bufA[SKEW(2048 - l)] = make_float2(Fe.x + Fo.y, Fo.x - Fe.y); // conj(Fe)+i conj(Fo)
    }
    __syncthreads();
    fft2048<1>(bufA, bufB);
    float2* op = (float2*)(out + (size_t)row * Ln);
    for (int n = tid; n < 2048; n += 256) {
        float2 z = bufA[SKEW(n)];
        float y0 = z.x * (1.0f / 2048.0f);
        float y1 = z.y * (1.0f / 2048.0f);
        op[n] = make_float2(0.5f * y0 * (1.0f + erff(y0 * 0.70710678118655f)),
                            0.5f * y1 * (1.0f + erff(y1 * 0.70710678118655f)));
    }
}

// ---------------------------------------------------------------------------
// mixmm: fp16 single-precision MFMA (no hi/lo split; fp16 rel err 2^-12
// contributes ~1 to absmax vs threshold 31 — round 5's 6-plane bf16 split
// was overkill and doubled weight traffic + tripled MFMA count).
// NT=16 cols/block, one batch; LDS 32 KB (Ustage 16 + Up 8 + Tp 8) -> up to
// 5 blocks/CU LDS-wise; launch_bounds(256,4): VGPR cap 128 (r4: (256,5)
// squeezed to 48 VGPRs and spilled 44 MB — do not tighten).
//   T = B2 @ U ; T *= mid(p,l)/64 ; W = (64*C2) @ T + D2 @ U
// MFMA f32_16x16x32_f16; layouts identical to bf16 (verified r3):
//   A[m=lane&15][k=quad*8+j], B[k=quad*8+j][n=lane&15], C/D col=lane&15,
//   row=quad*4+reg.
// ---------------------------------------------------------------------------
__device__ __forceinline__ f32x4 mfma16h(f16x8 a, f16x8 b, f32x4 c) {
    return __builtin_amdgcn_mfma_f32_16x16x32_f16(a, b, c, 0, 0, 0);
}
__device__ __forceinline__ f16x8 read_frag(const _Float16* plane, int n, int k) {
    int ksw = k ^ ((n & 7) << 3);
    return *(const f16x8*)(plane + n * 128 + ksw);
}
__device__ __forceinline__ f16x8 aread(const _Float16* W, int pl, int m, int k) {
    return *(const f16x8*)(W + pl * WPLSZ + m * 128 + k);
}
// complex acc += W * B : 4 MFMAs, planes {0:r, 1:i, 2:-i}
__device__ __forceinline__ void cmfma4(f16x8 Wr, f16x8 Wi, f16x8 Wni,
                                       f16x8 br, f16x8 bi, f32x4& aR, f32x4& aI) {
    aR = mfma16h(Wr, br, aR);
    aR = mfma16h(Wni, bi, aR);
    aI = mfma16h(Wr, bi, aI);
    aI = mfma16h(Wi, br, aI);
}

__global__ __launch_bounds__(256, 4) void mixmm_k(float2* __restrict__ Uhat,
                                                  const _Float16* __restrict__ W1,
                                                  const _Float16* __restrict__ W2,
                                                  const _Float16* __restrict__ W3,
                                                  const float* __restrict__ Lam) {
    __shared__ __align__(16) _Float16 Up[2 * PLSZ];      // 8 KB  {r, i}
    __shared__ __align__(16) _Float16 Tp[2 * PLSZ];      // 8 KB  {r, i}
    __shared__ __align__(16) float2 Ustage[128 * NT];    // 16 KB

    const int tid = threadIdx.x;
    const int b = blockIdx.x / NTILES;
    const int tile = blockIdx.x % NTILES;
    const int l0 = tile * NT;
    const int ncols = (LF - l0) < NT ? (LF - l0) : NT;

    // ---- load U tile (coalesced) ----
    for (int i = tid; i < 128 * NT; i += 256) {
        int h = i >> 4, n = i & 15;
        float2 v = make_float2(0.f, 0.f);
        if (n < ncols) v = Uhat[(size_t)(b * 128 + h) * LF + l0 + n];
        Ustage[h * NT + n] = v;
    }
    __syncthreads();

    // ---- convert to fp16 planes [n][k=h], XOR-swizzled ----
    {
        int n = tid & 15, kc = tid >> 4;   // kc 0..15: h = kc*8 + j
        f16x8 fr, fi;
        #pragma unroll
        for (int j = 0; j < 8; ++j) {
            float2 v = Ustage[(kc * 8 + j) * NT + n];
            fr[j] = (_Float16)v.x;
            fi[j] = (_Float16)v.y;
        }
        int ksw = (kc * 8) ^ ((n & 7) << 3);
        *(f16x8*)(Up + 0 * PLSZ + n * 128 + ksw) = fr;
        *(f16x8*)(Up + 1 * PLSZ + n * 128 + ksw) = fi;
    }
    __syncthreads();

    const int lane = tid & 63;
    const int w = tid >> 6;          // wave: m rows w*32 .. w*32+31
    const int m15 = lane & 15;
    const int quad = lane >> 4;

    f32x4 aR[2], aI[2];
    #pragma unroll
    for (int s = 0; s < 2; ++s) { aR[s] = (f32x4)0.f; aI[s] = (f32x4)0.f; }

    // ---- stage 1: T = B2 @ U ----
    #pragma unroll
    for (int kb = 0; kb < 4; ++kb) {
        int k = kb * 32 + quad * 8;
        f16x8 br = read_frag(Up + 0 * PLSZ, m15, k);
        f16x8 bi = read_frag(Up + 1 * PLSZ, m15, k);
        #pragma unroll
        for (int s = 0; s < 2; ++s) {
            int m = w * 32 + s * 16 + m15;
            cmfma4(aread(W1, 0, m, k), aread(W1, 1, m, k), aread(W1, 2, m, k),
                   br, bi, aR[s], aI[s]);
        }
    }

    // ---- Cauchy scale (x 1/TSCALE) + write T planes ----
    #pragma unroll
    for (int s = 0; s < 2; ++s) {
        #pragma unroll
        for (int reg = 0; reg < 4; ++reg) {
            int p = w * 32 + s * 16 + quad * 4 + reg;
            float2 lamv = ((const float2*)Lam)[p];
            float dr = -lamv.x;
            int n = m15;
            int l = l0 + n;
            float di = 3.14159265358979f * (float)l / 2048.0f - lamv.y;
            float inv = (1.0f / TSCALE) / (dr * dr + di * di);
            float xr = aR[s][reg], xi = aI[s][reg];
            float tr = (xr * dr + xi * di) * inv;
            float ti = (xi * dr - xr * di) * inv;
            int off = n * 128 + (p ^ ((n & 7) << 3));
            Tp[0 * PLSZ + off] = (_Float16)tr;
            Tp[1 * PLSZ + off] = (_Float16)ti;
        }
    }
    __syncthreads();   // T planes visible

    // ---- stage 2: W = (64*C2) @ T + D2 @ U ----
    #pragma unroll
    for (int s = 0; s < 2; ++s) { aR[s] = (f32x4)0.f; aI[s] = (f32x4)0.f; }

    #pragma unroll
    for (int kb = 0; kb < 4; ++kb) {
        int k = kb * 32 + quad * 8;
        f16x8 tr = read_frag(Tp + 0 * PLSZ, m15, k);
        f16x8 ti = read_frag(Tp + 1 * PLSZ, m15, k);
        f16x8 ur = read_frag(Up + 0 * PLSZ, m15, k);
        f16x8 ui = read_frag(Up + 1 * PLSZ, m15, k);
        #pragma unroll
        for (int s = 0; s < 2; ++s) {
            int m = w * 32 + s * 16 + m15;
            cmfma4(aread(W2, 0, m, k), aread(W2, 1, m, k), aread(W2, 2, m, k),
                   tr, ti, aR[s], aI[s]);
            cmfma4(aread(W3, 0, m, k), aread(W3, 1, m, k), aread(W3, 2, m, k),
                   ur, ui, aR[s], aI[s]);
        }
    }

    // ---- write W back to Uhat (block-disjoint tiles) ----
    #pragma unroll
    for (int s = 0; s < 2; ++s) {
        int n = m15;
        if (n < ncols) {
            #pragma unroll
            for (int reg = 0; reg < 4; ++reg) {
                int m = w * 32 + s * 16 + quad * 4 + reg;
                Uhat[(size_t)(b * 128 + m) * LF + l0 + n] = make_float2(aR[s][reg], aI[s][reg]);
            }
        }
    }
}

// ---------------------------------------------------------------------------
extern "C" void kernel_launch(void* const* d_in, const int* in_sizes, int n_in,
                              void* d_out, int out_size, void* d_ws, size_t ws_size,
                              hipStream_t stream) {
    const float* u    = (const float*)d_in[0];   // (B,H,L)
    const float* C_ri = (const float*)d_in[1];   // (H,P,2)
    const float* D_ri = (const float*)d_in[2];   // (H,H,2)
    const float* B_ri = (const float*)d_in[3];   // (P,H,2)
    const float* Lam  = (const float*)d_in[4];   // (P,2)
    float* out = (float*)d_out;

    float2* Uhat = (float2*)d_ws;                          // 1024*2049 float2 = 16 MiB
    _Float16* W1 = (_Float16*)(Uhat + (size_t)NROWS * LF);
    _Float16* W2 = W1 + 3 * WPLSZ;
    _Float16* W3 = W2 + 3 * WPLSZ;
    float2* Em = (float2*)(W3 + 3 * WPLSZ);

    prep_ABE_k<<<192, 256, 0, stream>>>(B_ri, C_ri, D_ri, W1, W2, Em);
    prep_W3_k<<<64, 256, 0, stream>>>(Em, W3);

    rfft_rows_k<<<NROWS, 256, 0, stream>>>(u, Uhat);
    mixmm_k<<<Bn * NTILES, 256, 0, stream>>>(Uhat, W1, W2, W3, Lam);
    irfft_gelu_k<<<NROWS, 256, 0, stream>>>(Uhat, out);
}

// Round 7
// 145.917 us; speedup vs baseline: 1.5039x; 1.1778x over previous
//
#include <hip/hip_runtime.h>
#include <math.h>

#define Bn 8
#define Hn 128
#define Pn 128
#define Ln 4096
#define LF 2049           // Ln/2 + 1
#define NROWS (Bn*Hn)     // 1024
#define NT 32             // frequency columns per mixmm block
#define NTILES 65         // ceil(2049/32) per batch
#define PLSZ 4096         // halfs per data plane (32 x 128)
#define WPLSZ 16384       // halfs per weight plane (128 x 128)
#define TSCALE 64.0f      // T stored as T/64 (fp16 range guard); W2 pre-scaled x64

// LDS skew for FFT buffers: +1 float2 every 16 -> strided Stockham writes <=2-way
#define SKEW(a) ((a) + ((a) >> 4))
#define FBUF 2176          // SKEW(2047)+1 rounded up

typedef _Float16 f16x8 __attribute__((ext_vector_type(8)));
typedef float f32x4 __attribute__((ext_vector_type(4)));

// ---------------------------------------------------------------------------
// prep: fold H-axis FFTs into weights; fp16 planes {0:r, 1:i},
// [m][k] row-major 128x128.  (third -i plane dropped: stage kernels keep a
// separate accM = Wi*bi accumulator and do R = accR - accM at the end)
//   W1[p][h] = (B_bar @ F)[p][h]               (stage 1: T = B2 @ U)
//   W2[h][p] = (Finv @ C)[h][p] * TSCALE       (stage 2: C2 @ T, T stored /64)
//   E [a][q] = (D @ F)[a][q]  (fp32 temp)
//   W3[h][q] = (Finv @ E)[h][q]                (stage 2: D2 @ U)
// ---------------------------------------------------------------------------
__device__ __forceinline__ void write2(_Float16* __restrict__ W, int idx,
                                       float vr, float vi) {
    W[0 * WPLSZ + idx] = (_Float16)vr;
    W[1 * WPLSZ + idx] = (_Float16)vi;
}

__global__ void prep_ABE_k(const float* __restrict__ B_ri, const float* __restrict__ C_ri,
                           const float* __restrict__ D_ri,
                           _Float16* __restrict__ W1, _Float16* __restrict__ W2,
                           float2* __restrict__ E) {
    int bid = blockIdx.x;
    int idx = (bid & 63) * 256 + threadIdx.x;   // 0..16383
    int rrow = idx >> 7, ccol = idx & 127;
    if (bid < 64) {
        // W1[p][h], p=rrow h=ccol
        float sr = 0.f, si = 0.f;
        for (int q = 0; q < 128; ++q) {
            float br = B_ri[(rrow * 128 + q) * 2 + 0];
            float bi = B_ri[(rrow * 128 + q) * 2 + 1];
            float ang = -3.14159265358979f * (float)((q * ccol) & 127) / 64.0f;
            float sw, cw; __sincosf(ang, &sw, &cw);
            sr += br * cw - bi * sw;
            si += br * sw + bi * cw;
        }
        write2(W1, idx, sr, si);
    } else if (bid < 128) {
        // W2[h][p], h=rrow p=ccol; x TSCALE/128
        float sr = 0.f, si = 0.f;
        for (int h2 = 0; h2 < 128; ++h2) {
            float cr = C_ri[(h2 * 128 + ccol) * 2 + 0];
            float ci = C_ri[(h2 * 128 + ccol) * 2 + 1];
            float ang = 3.14159265358979f * (float)((rrow * h2) & 127) / 64.0f;
            float sw, cw; __sincosf(ang, &sw, &cw);
            sr += cr * cw - ci * sw;
            si += cr * sw + ci * cw;
        }
        write2(W2, idx, sr * (TSCALE / 128.0f), si * (TSCALE / 128.0f));
    } else {
        // E[a][q], a=rrow q=ccol
        float sr = 0.f, si = 0.f;
        for (int c = 0; c < 128; ++c) {
            float dr = D_ri[(rrow * 128 + c) * 2 + 0];
            float di = D_ri[(rrow * 128 + c) * 2 + 1];
            float ang = -3.14159265358979f * (float)((c * ccol) & 127) / 64.0f;
            float sw, cw; __sincosf(ang, &sw, &cw);
            sr += dr * cw - di * sw;
            si += dr * sw + di * cw;
        }
        E[idx] = make_float2(sr, si);
    }
}

__global__ void prep_W3_k(const float2* __restrict__ E, _Float16* __restrict__ W3) {
    int idx = blockIdx.x * blockDim.x + threadIdx.x;   // h*128 + q
    int h = idx >> 7, q = idx & 127;
    float sr = 0.f, si = 0.f;
    for (int a = 0; a < 128; ++a) {
        float2 e = E[a * 128 + q];
        float ang = 3.14159265358979f * (float)((h * a) & 127) / 64.0f;
        float sw, cw; __sincosf(ang, &sw, &cw);
        sr += e.x * cw - e.y * sw;
        si += e.x * sw + e.y * cw;
    }
    write2(W3, idx, sr * (1.0f / 128.0f), si * (1.0f / 128.0f));
}

// ---------------------------------------------------------------------------
// 2048-pt Stockham FFT in LDS: radix-8 x3 + radix-4 (final, twiddle-free).
// Twiddles via one sincos + complex-mult recurrence (r4-vs-r5 A/B showed the
// recurrence is absmax-neutral; the error lives elsewhere).
// ---------------------------------------------------------------------------
__device__ __forceinline__ float2 cadd2(float2 a, float2 b) { return make_float2(a.x + b.x, a.y + b.y); }
__device__ __forceinline__ float2 csub2(float2 a, float2 b) { return make_float2(a.x - b.x, a.y - b.y); }

template <int SIGN>
__device__ __forceinline__ void dft4(float2 a0, float2 a1, float2 a2, float2 a3,
                                     float2& y0, float2& y1, float2& y2, float2& y3) {
    float t0x = a0.x + a2.x, t0y = a0.y + a2.y;
    float t1x = a0.x - a2.x, t1y = a0.y - a2.y;
    float t2x = a1.x + a3.x, t2y = a1.y + a3.y;
    float t3x = a1.x - a3.x, t3y = a1.y - a3.y;
    y0 = make_float2(t0x + t2x, t0y + t2y);
    y2 = make_float2(t0x - t2x, t0y - t2y);
    y1 = make_float2(t1x - (float)SIGN * t3y, t1y + (float)SIGN * t3x);
    y3 = make_float2(t1x + (float)SIGN * t3y, t1y - (float)SIGN * t3x);
}

template <int SIGN>
__device__ __forceinline__ void fft2048(float2* bufA, float2* bufB) {
    const int tid = threadIdx.x;
    float2* src = bufA;
    float2* dst = bufB;
    #pragma unroll
    for (int stg = 0; stg < 3; ++stg) {
        const int ls = 3 * stg;           // s = 8^stg
        const int k = tid;                // 256 butterflies
        const int q = k & ((1 << ls) - 1);
        const int p = k >> ls;
        float2 a[8];
        #pragma unroll
        for (int u = 0; u < 8; ++u) a[u] = src[SKEW(k + (u << 8))];
        float2 A0, A1, A2, A3, B0, B1, B2, B3;
        dft4<SIGN>(a[0], a[2], a[4], a[6], A0, A1, A2, A3);
        dft4<SIGN>(a[1], a[3], a[5], a[7], B0, B1, B2, B3);
        const float c45 = 0.70710678118655f;
        float2 w1 = make_float2(c45 * (B1.x - (float)SIGN * B1.y), c45 * ((float)SIGN * B1.x + B1.y));
        float2 w2 = make_float2(-(float)SIGN * B2.y, (float)SIGN * B2.x);
        float2 w3 = make_float2(c45 * (-B3.x - (float)SIGN * B3.y), c45 * ((float)SIGN * B3.x - B3.y));
        float2 b[8];
        b[0] = cadd2(A0, B0);  b[4] = csub2(A0, B0);
        b[1] = cadd2(A1, w1);  b[5] = csub2(A1, w1);
        b[2] = cadd2(A2, w2);  b[6] = csub2(A2, w2);
        b[3] = cadd2(A3, w3);  b[7] = csub2(A3, w3);
        float ang = (float)SIGN * 6.28318530717959f * (float)p * (1.0f / (float)(2048 >> ls));
        float s1, c1; __sincosf(ang, &s1, &c1);
        float cp = 1.f, sp = 0.f;
        #pragma unroll
        for (int j = 1; j < 8; ++j) {
            float cn = cp * c1 - sp * s1;
            float sn = cp * s1 + sp * c1;
            cp = cn; sp = sn;
            b[j] = make_float2(b[j].x * cp - b[j].y * sp, b[j].x * sp + b[j].y * cp);
        }
        const int base = q + (p << (ls + 3));
        #pragma unroll
        for (int j = 0; j < 8; ++j) dst[SKEW(base + (j << ls))] = b[j];
        __syncthreads();
        float2* t = src; src = dst; dst = t;
    }
    // final radix-4: s=512, m=1 -> p=0, twiddles = 1
    #pragma unroll
    for (int r = 0; r < 2; ++r) {
        int k = tid + (r << 8);
        float2 a0 = src[SKEW(k)];
        float2 a1 = src[SKEW(k + 512)];
        float2 a2 = src[SKEW(k + 1024)];
        float2 a3 = src[SKEW(k + 1536)];
        float2 y0, y1, y2, y3;
        dft4<SIGN>(a0, a1, a2, a3, y0, y1, y2, y3);
        dst[SKEW(k)] = y0;
        dst[SKEW(k + 512)] = y1;
        dst[SKEW(k + 1024)] = y2;
        dst[SKEW(k + 1536)] = y3;
    }
    __syncthreads();
    // stages: A->B, B->A, A->B, B->A  => result in bufA
}

// rfft via real-packing: z[n] = u[2n] + i u[2n+1]; U from Z by even/odd unpack.
__global__ __launch_bounds__(256, 4) void rfft_rows_k(const float* __restrict__ u,
                                                      float2* __restrict__ Uhat) {
    __shared__ __align__(16) float2 bufA[FBUF];
    __shared__ __align__(16) float2 bufB[FBUF];
    const int row = blockIdx.x;
    const int tid = threadIdx.x;
    const float4* up4 = (const float4*)(u + (size_t)row * Ln);
    #pragma unroll
    for (int r = 0; r < 4; ++r) {
        float4 v = up4[tid + (r << 8)];
        int i = 2 * (tid + (r << 8));
        bufA[SKEW(i)] = make_float2(v.x, v.y);
        bufA[SKEW(i + 1)] = make_float2(v.z, v.w);
    }
    __syncthreads();
    fft2048<-1>(bufA, bufB);
    float2* op = Uhat + (size_t)row * LF;
    for (int l = tid; l < 1025; l += 256) {
        float2 Zl = bufA[SKEW(l)];
        float2 Zm = bufA[SKEW((2048 - l) & 2047)];
        float2 Fe = make_float2(0.5f * (Zl.x + Zm.x), 0.5f * (Zl.y - Zm.y));
        float2 Dv = make_float2(0.5f * (Zl.x - Zm.x), 0.5f * (Zl.y + Zm.y));
        float2 Fo = make_float2(Dv.y, -Dv.x);                 // Dv / i
        float s, c; __sincosf(-3.14159265358979f * (float)l / 2048.0f, &s, &c);
        float2 TF = make_float2(Fo.x * c - Fo.y * s, Fo.x * s + Fo.y * c);
        op[l] = make_float2(Fe.x + TF.x, Fe.y + TF.y);
        op[2048 - l] = make_float2(Fe.x - TF.x, -(Fe.y - TF.y));   // conj(Fe - TF)
    }
}

// irfft via inverse packing: Z[l] = Fe + i Fo rebuilt from U, then 2048 IFFT,
// y[2n]=Re(z), y[2n+1]=Im(z), scale 1/2048, exact GELU. float4 stores.
__global__ __launch_bounds__(256, 4) void irfft_gelu_k(const float2* __restrict__ Uhat,
                                                       float* __restrict__ out) {
    __shared__ __align__(16) float2 bufA[FBUF];
    __shared__ __align__(16) float2 bufB[FBUF];
    const int row = blockIdx.x;
    const int tid = threadIdx.x;
    const float2* wp = Uhat + (size_t)row * LF;
    for (int l = tid; l < 1025; l += 256) {
        float2 Ul = wp[l];
        float2 Um = wp[2048 - l];
        float2 Fe = make_float2(0.5f * (Ul.x + Um.x), 0.5f * (Ul.y - Um.y));
        float2 Dv = make_float2(0.5f * (Ul.x - Um.x), 0.5f * (Ul.y + Um.y));
        float s, c; __sincosf(3.14159265358979f * (float)l / 2048.0f, &s, &c);
        float2 Fo = make_float2(Dv.x * c - Dv.y * s, Dv.x * s + Dv.y * c);
        bufA[SKEW(l)] = make_float2(Fe.x - Fo.y, Fe.y + Fo.x);          // Fe + i Fo
        if (l >= 1 && l <= 1023)
            bufA[SKEW(2048 - l)] = make_float2(Fe.x + Fo.y, Fo.x - Fe.y); // conj(Fe)+i conj(Fo)
    }
    __syncthreads();
    fft2048<1>(bufA, bufB);
    float4* op4 = (float4*)(out + (size_t)row * Ln);
    #pragma unroll
    for (int r = 0; r < 4; ++r) {
        int n = 2 * (tid + (r << 8));
        float2 z0 = bufA[SKEW(n)];
        float2 z1 = bufA[SKEW(n + 1)];
        float y0 = z0.x * (1.0f / 2048.0f);
        float y1 = z0.y * (1.0f / 2048.0f);
        float y2 = z1.x * (1.0f / 2048.0f);
        float y3 = z1.y * (1.0f / 2048.0f);
        op4[tid + (r << 8)] = make_float4(
            0.5f * y0 * (1.0f + erff(y0 * 0.70710678118655f)),
            0.5f * y1 * (1.0f + erff(y1 * 0.70710678118655f)),
            0.5f * y2 * (1.0f + erff(y2 * 0.70710678118655f)),
            0.5f * y3 * (1.0f + erff(y3 * 0.70710678118655f)));
    }
}

// ---------------------------------------------------------------------------
// mixmm: NT=32 columns/block (2 n-tiles per wave -> each weight fragment
// feeds 8 MFMAs, waves halve vs r6), one batch; grid 8*65=520.
// Weights are 2 planes {r,i}; R = accR - accM with accM = Wi*bi (kills the
// third plane's loads/traffic at the cost of 16 acc VGPRs).
// Per-kb weight loads batched into arrays BEFORE the MFMA burst so the
// allocator keeps >=4 loads in flight (r6: 48 VGPRs, loads serialized at
// ~250 cyc each = the whole 59 us).
// LDS 32 KB (2x 8KB planes x2); launch_bounds(256,4) VGPR cap 128 (r4: do
// not tighten past this — spill catastrophe).
//   T = B2 @ U ; T *= mid(p,l)/64 ; W = (64*C2) @ T + D2 @ U
// MFMA f32_16x16x32_f16, layouts verified r3.
// ---------------------------------------------------------------------------
__device__ __forceinline__ f32x4 mfma16h(f16x8 a, f16x8 b, f32x4 c) {
    return __builtin_amdgcn_mfma_f32_16x16x32_f16(a, b, c, 0, 0, 0);
}
__device__ __forceinline__ f16x8 read_frag(const _Float16* plane, int n, int k) {
    int ksw = k ^ ((n & 7) << 3);
    return *(const f16x8*)(plane + n * 128 + ksw);
}
__device__ __forceinline__ f16x8 aread(const _Float16* W, int pl, int m, int k) {
    return *(const f16x8*)(W + pl * WPLSZ + m * 128 + k);
}

__global__ __launch_bounds__(256, 4) void mixmm_k(float2* __restrict__ Uhat,
                                                  const _Float16* __restrict__ W1,
                                                  const _Float16* __restrict__ W2,
                                                  const _Float16* __restrict__ W3,
                                                  const float* __restrict__ Lam) {
    __shared__ __align__(16) _Float16 Up[2 * PLSZ];      // 16 KB  {r, i}
    __shared__ __align__(16) _Float16 Tp[2 * PLSZ];      // 16 KB  {r, i}

    const int tid = threadIdx.x;
    const int b = blockIdx.x / NTILES;
    const int tile = blockIdx.x % NTILES;
    const int l0 = tile * NT;
    const int ncols = (LF - l0) < NT ? (LF - l0) : NT;

    // ---- direct load U tile -> fp16 planes [n][k=h], XOR-swizzled ----
    // thread: n = tid&31, kc = tid>>5 (0..7) owns h = kc*16 .. kc*16+15.
    // same-kc threads read 32 consecutive float2 per h -> 256B coalesced.
    {
        int n = tid & 31, kc = tid >> 5;
        float2 v[16];
        #pragma unroll
        for (int j = 0; j < 16; ++j) {
            int h = kc * 16 + j;
            v[j] = (n < ncols) ? Uhat[(size_t)(b * 128 + h) * LF + l0 + n]
                               : make_float2(0.f, 0.f);
        }
        #pragma unroll
        for (int jc = 0; jc < 2; ++jc) {
            f16x8 fr, fi;
            #pragma unroll
            for (int j = 0; j < 8; ++j) {
                fr[j] = (_Float16)v[jc * 8 + j].x;
                fi[j] = (_Float16)v[jc * 8 + j].y;
            }
            int ksw = (kc * 16 + jc * 8) ^ ((n & 7) << 3);
            *(f16x8*)(Up + 0 * PLSZ + n * 128 + ksw) = fr;
            *(f16x8*)(Up + 1 * PLSZ + n * 128 + ksw) = fi;
        }
    }
    __syncthreads();

    const int lane = tid & 63;
    const int w = tid >> 6;          // wave: m rows w*32 .. w*32+31
    const int m15 = lane & 15;
    const int quad = lane >> 4;

    f32x4 accR[2][2], accM[2][2], accI[2][2];   // [s][t]
    #pragma unroll
    for (int s = 0; s < 2; ++s)
        #pragma unroll
        for (int t = 0; t < 2; ++t) {
            accR[s][t] = (f32x4)0.f; accM[s][t] = (f32x4)0.f; accI[s][t] = (f32x4)0.f;
        }

    // ---- stage 1: T = B2 @ U ----
    #pragma unroll
    for (int kb = 0; kb < 4; ++kb) {
        int k = kb * 32 + quad * 8;
        f16x8 wr[2], wi[2];
        #pragma unroll
        for (int s = 0; s < 2; ++s) {
            int m = w * 32 + s * 16 + m15;
            wr[s] = aread(W1, 0, m, k);
            wi[s] = aread(W1, 1, m, k);
        }
        f16x8 br[2], bi[2];
        #pragma unroll
        for (int t = 0; t < 2; ++t) {
            br[t] = read_frag(Up + 0 * PLSZ, t * 16 + m15, k);
            bi[t] = read_frag(Up + 1 * PLSZ, t * 16 + m15, k);
        }
        #pragma unroll
        for (int s = 0; s < 2; ++s)
            #pragma unroll
            for (int t = 0; t < 2; ++t) {
                accR[s][t] = mfma16h(wr[s], br[t], accR[s][t]);
                accM[s][t] = mfma16h(wi[s], bi[t], accM[s][t]);
                accI[s][t] = mfma16h(wr[s], bi[t], accI[s][t]);
                accI[s][t] = mfma16h(wi[s], br[t], accI[s][t]);
            }
    }

    // ---- Cauchy scale (x 1/TSCALE) + write T planes ----
    #pragma unroll
    for (int s = 0; s < 2; ++s) {
        #pragma unroll
        for (int reg = 0; reg < 4; ++reg) {
            int p = w * 32 + s * 16 + quad * 4 + reg;
            float2 lamv = ((const float2*)Lam)[p];
            float dr = -lamv.x;
            #pragma unroll
            for (int t = 0; t < 2; ++t) {
                int n = t * 16 + m15;
                int l = l0 + n;
                float di = 3.14159265358979f * (float)l / 2048.0f - lamv.y;
                float inv = (1.0f / TSCALE) / (dr * dr + di * di);
                float xr = accR[s][t][reg] - accM[s][t][reg];
                float xi = accI[s][t][reg];
                float tr = (xr * dr + xi * di) * inv;
                float ti = (xi * dr - xr * di) * inv;
                int off = n * 128 + (p ^ ((n & 7) << 3));
                Tp[0 * PLSZ + off] = (_Float16)tr;
                Tp[1 * PLSZ + off] = (_Float16)ti;
            }
        }
    }
    __syncthreads();   // T planes visible

    // ---- stage 2: W = (64*C2) @ T + D2 @ U ----
    #pragma unroll
    for (int s = 0; s < 2; ++s)
        #pragma unroll
        for (int t = 0; t < 2; ++t) {
            accR[s][t] = (f32x4)0.f; accM[s][t] = (f32x4)0.f; accI[s][t] = (f32x4)0.f;
        }

    #pragma unroll
    for (int kb = 0; kb < 4; ++kb) {
        int k = kb * 32 + quad * 8;
        // -- C2 @ T --
        {
            f16x8 wr[2], wi[2];
            #pragma unroll
            for (int s = 0; s < 2; ++s) {
                int m = w * 32 + s * 16 + m15;
                wr[s] = aread(W2, 0, m, k);
                wi[s] = aread(W2, 1, m, k);
            }
            f16x8 br[2], bi[2];
            #pragma unroll
            for (int t = 0; t < 2; ++t) {
                br[t] = read_frag(Tp + 0 * PLSZ, t * 16 + m15, k);
                bi[t] = read_frag(Tp + 1 * PLSZ, t * 16 + m15, k);
            }
            #pragma unroll
            for (int s = 0; s < 2; ++s)
                #pragma unroll
                for (int t = 0; t < 2; ++t) {
                    accR[s][t] = mfma16h(wr[s], br[t], accR[s][t]);
                    accM[s][t] = mfma16h(wi[s], bi[t], accM[s][t]);
                    accI[s][t] = mfma16h(wr[s], bi[t], accI[s][t]);
                    accI[s][t] = mfma16h(wi[s], br[t], accI[s][t]);
                }
        }
        // -- D2 @ U --
        {
            f16x8 wr[2], wi[2];
            #pragma unroll
            for (int s = 0; s < 2; ++s) {
                int m = w * 32 + s * 16 + m15;
                wr[s] = aread(W3, 0, m, k);
                wi[s] = aread(W3, 1, m, k);
            }
            f16x8 br[2], bi[2];
            #pragma unroll
            for (int t = 0; t < 2; ++t) {
                br[t] = read_frag(Up + 0 * PLSZ, t * 16 + m15, k);
                bi[t] = read_frag(Up + 1 * PLSZ, t * 16 + m15, k);
            }
            #pragma unroll
            for (int s = 0; s < 2; ++s)
                #pragma unroll
                for (int t = 0; t < 2; ++t) {
                    accR[s][t] = mfma16h(wr[s], br[t], accR[s][t]);
                    accM[s][t] = mfma16h(wi[s], bi[t], accM[s][t]);
                    accI[s][t] = mfma16h(wr[s], bi[t], accI[s][t]);
                    accI[s][t] = mfma16h(wi[s], br[t], accI[s][t]);
                }
        }
    }

    // ---- write W back to Uhat (block-disjoint tiles) ----
    #pragma unroll
    for (int s = 0; s < 2; ++s) {
        #pragma unroll
        for (int t = 0; t < 2; ++t) {
            int n = t * 16 + m15;
            if (n < ncols) {
                #pragma unroll
                for (int reg = 0; reg < 4; ++reg) {
                    int m = w * 32 + s * 16 + quad * 4 + reg;
                    Uhat[(size_t)(b * 128 + m) * LF + l0 + n] =
                        make_float2(accR[s][t][reg] - accM[s][t][reg], accI[s][t][reg]);
                }
            }
        }
    }
}

// ---------------------------------------------------------------------------
extern "C" void kernel_launch(void* const* d_in, const int* in_sizes, int n_in,
                              void* d_out, int out_size, void* d_ws, size_t ws_size,
                              hipStream_t stream) {
    const float* u    = (const float*)d_in[0];   // (B,H,L)
    const float* C_ri = (const float*)d_in[1];   // (H,P,2)
    const float* D_ri = (const float*)d_in[2];   // (H,H,2)
    const float* B_ri = (const float*)d_in[3];   // (P,H,2)
    const float* Lam  = (const float*)d_in[4];   // (P,2)
    float* out = (float*)d_out;

    float2* Uhat = (float2*)d_ws;                          // 1024*2049 float2 = 16 MiB
    _Float16* W1 = (_Float16*)(Uhat + (size_t)NROWS * LF);
    _Float16* W2 = W1 + 2 * WPLSZ;
    _Float16* W3 = W2 + 2 * WPLSZ;
    float2* Em = (float2*)(W3 + 2 * WPLSZ);

    prep_ABE_k<<<192, 256, 0, stream>>>(B_ri, C_ri, D_ri, W1, W2, Em);
    prep_W3_k<<<64, 256, 0, stream>>>(Em, W3);

    rfft_rows_k<<<NROWS, 256, 0, stream>>>(u, Uhat);
    mixmm_k<<<Bn * NTILES, 256, 0, stream>>>(Uhat, W1, W2, W3, Lam);
    irfft_gelu_k<<<NROWS, 256, 0, stream>>>(Uhat, out);
}

// Round 8
// 144.487 us; speedup vs baseline: 1.5188x; 1.0099x over previous
//
#include <hip/hip_runtime.h>
#include <math.h>

#define Bn 8
#define Hn 128
#define Pn 128
#define Ln 4096
#define LF 2049           // Ln/2 + 1
#define NROWS (Bn*Hn)     // 1024
#define NT 32             // frequency columns per mixmm block
#define NTILES 65         // ceil(2049/32) per batch
#define PLSZ 4096         // halfs per data plane (32 x 128)
#define WPLSZ 16384       // halfs per weight plane (128 x 128)
#define TSCALE 64.0f      // T stored as T/64 (fp16 range guard); W2 pre-scaled x64

// LDS skew for FFT buffers: +1 float2 every 16 -> strided Stockham writes <=2-way
#define SKEW(a) ((a) + ((a) >> 4))
#define FBUF 2176          // SKEW(2047)+1 rounded up

typedef _Float16 f16x8 __attribute__((ext_vector_type(8)));
typedef float f32x4 __attribute__((ext_vector_type(4)));

// Fast HW sin/cos: __sinf/__cosf lower to the native v_sin_f32/v_cos_f32 path
// (~3 insts, 1/4-rate, ~4 ULP). __sincosf lowers to the OCML correctly-rounded
// sincos with full range reduction (~60-100 insts) — r7 theory: that library
// call was the FFT+prep VALU bloat.
__device__ __forceinline__ void fsincos(float a, float* s, float* c) {
    *s = __sinf(a);
    *c = __cosf(a);
}

// ---------------------------------------------------------------------------
// prep: fold H-axis FFTs into weights; fp16 planes {0:r, 1:i},
// [m][k] row-major 128x128.  (stage kernels keep accM = Wi*bi separately and
// do R = accR - accM, so no third plane)
//   W1[p][h] = (B_bar @ F)[p][h]               (stage 1: T = B2 @ U)
//   W2[h][p] = (Finv @ C)[h][p] * TSCALE       (stage 2: C2 @ T, T stored /64)
//   E [a][q] = (D @ F)[a][q]  (fp32 temp)
//   W3[h][q] = (Finv @ E)[h][q]                (stage 2: D2 @ U)
// ---------------------------------------------------------------------------
__device__ __forceinline__ void write2(_Float16* __restrict__ W, int idx,
                                       float vr, float vi) {
    W[0 * WPLSZ + idx] = (_Float16)vr;
    W[1 * WPLSZ + idx] = (_Float16)vi;
}

__global__ void prep_ABE_k(const float* __restrict__ B_ri, const float* __restrict__ C_ri,
                           const float* __restrict__ D_ri,
                           _Float16* __restrict__ W1, _Float16* __restrict__ W2,
                           float2* __restrict__ E) {
    int bid = blockIdx.x;
    int idx = (bid & 63) * 256 + threadIdx.x;   // 0..16383
    int rrow = idx >> 7, ccol = idx & 127;
    if (bid < 64) {
        // W1[p][h], p=rrow h=ccol
        float sr = 0.f, si = 0.f;
        for (int q = 0; q < 128; ++q) {
            float br = B_ri[(rrow * 128 + q) * 2 + 0];
            float bi = B_ri[(rrow * 128 + q) * 2 + 1];
            float ang = -3.14159265358979f * (float)((q * ccol) & 127) / 64.0f;
            float sw, cw; fsincos(ang, &sw, &cw);
            sr += br * cw - bi * sw;
            si += br * sw + bi * cw;
        }
        write2(W1, idx, sr, si);
    } else if (bid < 128) {
        // W2[h][p], h=rrow p=ccol; x TSCALE/128
        float sr = 0.f, si = 0.f;
        for (int h2 = 0; h2 < 128; ++h2) {
            float cr = C_ri[(h2 * 128 + ccol) * 2 + 0];
            float ci = C_ri[(h2 * 128 + ccol) * 2 + 1];
            float ang = 3.14159265358979f * (float)((rrow * h2) & 127) / 64.0f;
            float sw, cw; fsincos(ang, &sw, &cw);
            sr += cr * cw - ci * sw;
            si += cr * sw + ci * cw;
        }
        write2(W2, idx, sr * (TSCALE / 128.0f), si * (TSCALE / 128.0f));
    } else {
        // E[a][q], a=rrow q=ccol
        float sr = 0.f, si = 0.f;
        for (int c = 0; c < 128; ++c) {
            float dr = D_ri[(rrow * 128 + c) * 2 + 0];
            float di = D_ri[(rrow * 128 + c) * 2 + 1];
            float ang = -3.14159265358979f * (float)((c * ccol) & 127) / 64.0f;
            float sw, cw; fsincos(ang, &sw, &cw);
            sr += dr * cw - di * sw;
            si += dr * sw + di * cw;
        }
        E[idx] = make_float2(sr, si);
    }
}

__global__ void prep_W3_k(const float2* __restrict__ E, _Float16* __restrict__ W3) {
    int idx = blockIdx.x * blockDim.x + threadIdx.x;   // h*128 + q
    int h = idx >> 7, q = idx & 127;
    float sr = 0.f, si = 0.f;
    for (int a = 0; a < 128; ++a) {
        float2 e = E[a * 128 + q];
        float ang = 3.14159265358979f * (float)((h * a) & 127) / 64.0f;
        float sw, cw; fsincos(ang, &sw, &cw);
        sr += e.x * cw - e.y * sw;
        si += e.x * sw + e.y * cw;
    }
    write2(W3, idx, sr * (1.0f / 128.0f), si * (1.0f / 128.0f));
}

// ---------------------------------------------------------------------------
// 2048-pt Stockham FFT in LDS: radix-8 x3 + radix-4 (final, twiddle-free).
// Twiddles: exact per-j native sin/cos (cheap now; also kills the serial
// recurrence chain).
// ---------------------------------------------------------------------------
__device__ __forceinline__ float2 cadd2(float2 a, float2 b) { return make_float2(a.x + b.x, a.y + b.y); }
__device__ __forceinline__ float2 csub2(float2 a, float2 b) { return make_float2(a.x - b.x, a.y - b.y); }

template <int SIGN>
__device__ __forceinline__ void dft4(float2 a0, float2 a1, float2 a2, float2 a3,
                                     float2& y0, float2& y1, float2& y2, float2& y3) {
    float t0x = a0.x + a2.x, t0y = a0.y + a2.y;
    float t1x = a0.x - a2.x, t1y = a0.y - a2.y;
    float t2x = a1.x + a3.x, t2y = a1.y + a3.y;
    float t3x = a1.x - a3.x, t3y = a1.y - a3.y;
    y0 = make_float2(t0x + t2x, t0y + t2y);
    y2 = make_float2(t0x - t2x, t0y - t2y);
    y1 = make_float2(t1x - (float)SIGN * t3y, t1y + (float)SIGN * t3x);
    y3 = make_float2(t1x + (float)SIGN * t3y, t1y - (float)SIGN * t3x);
}

template <int SIGN>
__device__ __forceinline__ void fft2048(float2* bufA, float2* bufB) {
    const int tid = threadIdx.x;
    float2* src = bufA;
    float2* dst = bufB;
    #pragma unroll
    for (int stg = 0; stg < 3; ++stg) {
        const int ls = 3 * stg;           // s = 8^stg
        const int k = tid;                // 256 butterflies
        const int q = k & ((1 << ls) - 1);
        const int p = k >> ls;
        float2 a[8];
        #pragma unroll
        for (int u = 0; u < 8; ++u) a[u] = src[SKEW(k + (u << 8))];
        float2 A0, A1, A2, A3, B0, B1, B2, B3;
        dft4<SIGN>(a[0], a[2], a[4], a[6], A0, A1, A2, A3);
        dft4<SIGN>(a[1], a[3], a[5], a[7], B0, B1, B2, B3);
        const float c45 = 0.70710678118655f;
        float2 w1 = make_float2(c45 * (B1.x - (float)SIGN * B1.y), c45 * ((float)SIGN * B1.x + B1.y));
        float2 w2 = make_float2(-(float)SIGN * B2.y, (float)SIGN * B2.x);
        float2 w3 = make_float2(c45 * (-B3.x - (float)SIGN * B3.y), c45 * ((float)SIGN * B3.x - B3.y));
        float2 b[8];
        b[0] = cadd2(A0, B0);  b[4] = csub2(A0, B0);
        b[1] = cadd2(A1, w1);  b[5] = csub2(A1, w1);
        b[2] = cadd2(A2, w2);  b[6] = csub2(A2, w2);
        b[3] = cadd2(A3, w3);  b[7] = csub2(A3, w3);
        float ang = (float)SIGN * 6.28318530717959f * (float)p * (1.0f / (float)(2048 >> ls));
        #pragma unroll
        for (int j = 1; j < 8; ++j) {
            float sj, cj; fsincos((float)j * ang, &sj, &cj);
            b[j] = make_float2(b[j].x * cj - b[j].y * sj, b[j].x * sj + b[j].y * cj);
        }
        const int base = q + (p << (ls + 3));
        #pragma unroll
        for (int j = 0; j < 8; ++j) dst[SKEW(base + (j << ls))] = b[j];
        __syncthreads();
        float2* t = src; src = dst; dst = t;
    }
    // final radix-4: s=512, m=1 -> p=0, twiddles = 1
    #pragma unroll
    for (int r = 0; r < 2; ++r) {
        int k = tid + (r << 8);
        float2 a0 = src[SKEW(k)];
        float2 a1 = src[SKEW(k + 512)];
        float2 a2 = src[SKEW(k + 1024)];
        float2 a3 = src[SKEW(k + 1536)];
        float2 y0, y1, y2, y3;
        dft4<SIGN>(a0, a1, a2, a3, y0, y1, y2, y3);
        dst[SKEW(k)] = y0;
        dst[SKEW(k + 512)] = y1;
        dst[SKEW(k + 1024)] = y2;
        dst[SKEW(k + 1536)] = y3;
    }
    __syncthreads();
    // stages: A->B, B->A, A->B, B->A  => result in bufA
}

// rfft via real-packing: z[n] = u[2n] + i u[2n+1]; U from Z by even/odd unpack.
__global__ __launch_bounds__(256, 4) void rfft_rows_k(const float* __restrict__ u,
                                                      float2* __restrict__ Uhat) {
    __shared__ __align__(16) float2 bufA[FBUF];
    __shared__ __align__(16) float2 bufB[FBUF];
    const int row = blockIdx.x;
    const int tid = threadIdx.x;
    const float4* up4 = (const float4*)(u + (size_t)row * Ln);
    #pragma unroll
    for (int r = 0; r < 4; ++r) {
        float4 v = up4[tid + (r << 8)];
        int i = 2 * (tid + (r << 8));
        bufA[SKEW(i)] = make_float2(v.x, v.y);
        bufA[SKEW(i + 1)] = make_float2(v.z, v.w);
    }
    __syncthreads();
    fft2048<-1>(bufA, bufB);
    float2* op = Uhat + (size_t)row * LF;
    for (int l = tid; l < 1025; l += 256) {
        float2 Zl = bufA[SKEW(l)];
        float2 Zm = bufA[SKEW((2048 - l) & 2047)];
        float2 Fe = make_float2(0.5f * (Zl.x + Zm.x), 0.5f * (Zl.y - Zm.y));
        float2 Dv = make_float2(0.5f * (Zl.x - Zm.x), 0.5f * (Zl.y + Zm.y));
        float2 Fo = make_float2(Dv.y, -Dv.x);                 // Dv / i
        float s, c; fsincos(-3.14159265358979f * (float)l / 2048.0f, &s, &c);
        float2 TF = make_float2(Fo.x * c - Fo.y * s, Fo.x * s + Fo.y * c);
        op[l] = make_float2(Fe.x + TF.x, Fe.y + TF.y);
        op[2048 - l] = make_float2(Fe.x - TF.x, -(Fe.y - TF.y));   // conj(Fe - TF)
    }
}

// irfft via inverse packing: Z[l] = Fe + i Fo rebuilt from U, then 2048 IFFT,
// y[2n]=Re(z), y[2n+1]=Im(z), scale 1/2048, exact GELU. float4 stores.
__global__ __launch_bounds__(256, 4) void irfft_gelu_k(const float2* __restrict__ Uhat,
                                                       float* __restrict__ out) {
    __shared__ __align__(16) float2 bufA[FBUF];
    __shared__ __align__(16) float2 bufB[FBUF];
    const int row = blockIdx.x;
    const int tid = threadIdx.x;
    const float2* wp = Uhat + (size_t)row * LF;
    for (int l = tid; l < 1025; l += 256) {
        float2 Ul = wp[l];
        float2 Um = wp[2048 - l];
        float2 Fe = make_float2(0.5f * (Ul.x + Um.x), 0.5f * (Ul.y - Um.y));
        float2 Dv = make_float2(0.5f * (Ul.x - Um.x), 0.5f * (Ul.y + Um.y));
        float s, c; fsincos(3.14159265358979f * (float)l / 2048.0f, &s, &c);
        float2 Fo = make_float2(Dv.x * c - Dv.y * s, Dv.x * s + Dv.y * c);
        bufA[SKEW(l)] = make_float2(Fe.x - Fo.y, Fe.y + Fo.x);          // Fe + i Fo
        if (l >= 1 && l <= 1023)
            bufA[SKEW(2048 - l)] = make_float2(Fe.x + Fo.y, Fo.x - Fe.y); // conj(Fe)+i conj(Fo)
    }
    __syncthreads();
    fft2048<1>(bufA, bufB);
    float4* op4 = (float4*)(out + (size_t)row * Ln);
    #pragma unroll
    for (int r = 0; r < 4; ++r) {
        int n = 2 * (tid + (r << 8));
        float2 z0 = bufA[SKEW(n)];
        float2 z1 = bufA[SKEW(n + 1)];
        float y0 = z0.x * (1.0f / 2048.0f);
        float y1 = z0.y * (1.0f / 2048.0f);
        float y2 = z1.x * (1.0f / 2048.0f);
        float y3 = z1.y * (1.0f / 2048.0f);
        op4[tid + (r << 8)] = make_float4(
            0.5f * y0 * (1.0f + erff(y0 * 0.70710678118655f)),
            0.5f * y1 * (1.0f + erff(y1 * 0.70710678118655f)),
            0.5f * y2 * (1.0f + erff(y2 * 0.70710678118655f)),
            0.5f * y3 * (1.0f + erff(y3 * 0.70710678118655f)));
    }
}

// ---------------------------------------------------------------------------
// mixmm: NT=32 columns/block (unchanged from r7 — 59 -> ~sub-30 us).
// ---------------------------------------------------------------------------
__device__ __forceinline__ f32x4 mfma16h(f16x8 a, f16x8 b, f32x4 c) {
    return __builtin_amdgcn_mfma_f32_16x16x32_f16(a, b, c, 0, 0, 0);
}
__device__ __forceinline__ f16x8 read_frag(const _Float16* plane, int n, int k) {
    int ksw = k ^ ((n & 7) << 3);
    return *(const f16x8*)(plane + n * 128 + ksw);
}
__device__ __forceinline__ f16x8 aread(const _Float16* W, int pl, int m, int k) {
    return *(const f16x8*)(W + pl * WPLSZ + m * 128 + k);
}

__global__ __launch_bounds__(256, 4) void mixmm_k(float2* __restrict__ Uhat,
                                                  const _Float16* __restrict__ W1,
                                                  const _Float16* __restrict__ W2,
                                                  const _Float16* __restrict__ W3,
                                                  const float* __restrict__ Lam) {
    __shared__ __align__(16) _Float16 Up[2 * PLSZ];      // 16 KB  {r, i}
    __shared__ __align__(16) _Float16 Tp[2 * PLSZ];      // 16 KB  {r, i}

    const int tid = threadIdx.x;
    const int b = blockIdx.x / NTILES;
    const int tile = blockIdx.x % NTILES;
    const int l0 = tile * NT;
    const int ncols = (LF - l0) < NT ? (LF - l0) : NT;

    // ---- direct load U tile -> fp16 planes [n][k=h], XOR-swizzled ----
    {
        int n = tid & 31, kc = tid >> 5;
        float2 v[16];
        #pragma unroll
        for (int j = 0; j < 16; ++j) {
            int h = kc * 16 + j;
            v[j] = (n < ncols) ? Uhat[(size_t)(b * 128 + h) * LF + l0 + n]
                               : make_float2(0.f, 0.f);
        }
        #pragma unroll
        for (int jc = 0; jc < 2; ++jc) {
            f16x8 fr, fi;
            #pragma unroll
            for (int j = 0; j < 8; ++j) {
                fr[j] = (_Float16)v[jc * 8 + j].x;
                fi[j] = (_Float16)v[jc * 8 + j].y;
            }
            int ksw = (kc * 16 + jc * 8) ^ ((n & 7) << 3);
            *(f16x8*)(Up + 0 * PLSZ + n * 128 + ksw) = fr;
            *(f16x8*)(Up + 1 * PLSZ + n * 128 + ksw) = fi;
        }
    }
    __syncthreads();

    const int lane = tid & 63;
    const int w = tid >> 6;          // wave: m rows w*32 .. w*32+31
    const int m15 = lane & 15;
    const int quad = lane >> 4;

    f32x4 accR[2][2], accM[2][2], accI[2][2];   // [s][t]
    #pragma unroll
    for (int s = 0; s < 2; ++s)
        #pragma unroll
        for (int t = 0; t < 2; ++t) {
            accR[s][t] = (f32x4)0.f; accM[s][t] = (f32x4)0.f; accI[s][t] = (f32x4)0.f;
        }

    // ---- stage 1: T = B2 @ U ----
    #pragma unroll
    for (int kb = 0; kb < 4; ++kb) {
        int k = kb * 32 + quad * 8;
        f16x8 wr[2], wi[2];
        #pragma unroll
        for (int s = 0; s < 2; ++s) {
            int m = w * 32 + s * 16 + m15;
            wr[s] = aread(W1, 0, m, k);
            wi[s] = aread(W1, 1, m, k);
        }
        f16x8 br[2], bi[2];
        #pragma unroll
        for (int t = 0; t < 2; ++t) {
            br[t] = read_frag(Up + 0 * PLSZ, t * 16 + m15, k);
            bi[t] = read_frag(Up + 1 * PLSZ, t * 16 + m15, k);
        }
        #pragma unroll
        for (int s = 0; s < 2; ++s)
            #pragma unroll
            for (int t = 0; t < 2; ++t) {
                accR[s][t] = mfma16h(wr[s], br[t], accR[s][t]);
                accM[s][t] = mfma16h(wi[s], bi[t], accM[s][t]);
                accI[s][t] = mfma16h(wr[s], bi[t], accI[s][t]);
                accI[s][t] = mfma16h(wi[s], br[t], accI[s][t]);
            }
    }

    // ---- Cauchy scale (x 1/TSCALE) + write T planes ----
    #pragma unroll
    for (int s = 0; s < 2; ++s) {
        #pragma unroll
        for (int reg = 0; reg < 4; ++reg) {
            int p = w * 32 + s * 16 + quad * 4 + reg;
            float2 lamv = ((const float2*)Lam)[p];
            float dr = -lamv.x;
            #pragma unroll
            for (int t = 0; t < 2; ++t) {
                int n = t * 16 + m15;
                int l = l0 + n;
                float di = 3.14159265358979f * (float)l / 2048.0f - lamv.y;
                float inv = (1.0f / TSCALE) / (dr * dr + di * di);
                float xr = accR[s][t][reg] - accM[s][t][reg];
                float xi = accI[s][t][reg];
                float tr = (xr * dr + xi * di) * inv;
                float ti = (xi * dr - xr * di) * inv;
                int off = n * 128 + (p ^ ((n & 7) << 3));
                Tp[0 * PLSZ + off] = (_Float16)tr;
                Tp[1 * PLSZ + off] = (_Float16)ti;
            }
        }
    }
    __syncthreads();   // T planes visible

    // ---- stage 2: W = (64*C2) @ T + D2 @ U ----
    #pragma unroll
    for (int s = 0; s < 2; ++s)
        #pragma unroll
        for (int t = 0; t < 2; ++t) {
            accR[s][t] = (f32x4)0.f; accM[s][t] = (f32x4)0.f; accI[s][t] = (f32x4)0.f;
        }

    #pragma unroll
    for (int kb = 0; kb < 4; ++kb) {
        int k = kb * 32 + quad * 8;
        // -- C2 @ T --
        {
            f16x8 wr[2], wi[2];
            #pragma unroll
            for (int s = 0; s < 2; ++s) {
                int m = w * 32 + s * 16 + m15;
                wr[s] = aread(W2, 0, m, k);
                wi[s] = aread(W2, 1, m, k);
            }
            f16x8 br[2], bi[2];
            #pragma unroll
            for (int t = 0; t < 2; ++t) {
                br[t] = read_frag(Tp + 0 * PLSZ, t * 16 + m15, k);
                bi[t] = read_frag(Tp + 1 * PLSZ, t * 16 + m15, k);
            }
            #pragma unroll
            for (int s = 0; s < 2; ++s)
                #pragma unroll
                for (int t = 0; t < 2; ++t) {
                    accR[s][t] = mfma16h(wr[s], br[t], accR[s][t]);
                    accM[s][t] = mfma16h(wi[s], bi[t], accM[s][t]);
                    accI[s][t] = mfma16h(wr[s], bi[t], accI[s][t]);
                    accI[s][t] = mfma16h(wi[s], br[t], accI[s][t]);
                }
        }
        // -- D2 @ U --
        {
            f16x8 wr[2], wi[2];
            #pragma unroll
            for (int s = 0; s < 2; ++s) {
                int m = w * 32 + s * 16 + m15;
                wr[s] = aread(W3, 0, m, k);
                wi[s] = aread(W3, 1, m, k);
            }
            f16x8 br[2], bi[2];
            #pragma unroll
            for (int t = 0; t < 2; ++t) {
                br[t] = read_frag(Up + 0 * PLSZ, t * 16 + m15, k);
                bi[t] = read_frag(Up + 1 * PLSZ, t * 16 + m15, k);
            }
            #pragma unroll
            for (int s = 0; s < 2; ++s)
                #pragma unroll
                for (int t = 0; t < 2; ++t) {
                    accR[s][t] = mfma16h(wr[s], br[t], accR[s][t]);
                    accM[s][t] = mfma16h(wi[s], bi[t], accM[s][t]);
                    accI[s][t] = mfma16h(wr[s], bi[t], accI[s][t]);
                    accI[s][t] = mfma16h(wi[s], br[t], accI[s][t]);
                }
        }
    }

    // ---- write W back to Uhat (block-disjoint tiles) ----
    #pragma unroll
    for (int s = 0; s < 2; ++s) {
        #pragma unroll
        for (int t = 0; t < 2; ++t) {
            int n = t * 16 + m15;
            if (n < ncols) {
                #pragma unroll
                for (int reg = 0; reg < 4; ++reg) {
                    int m = w * 32 + s * 16 + quad * 4 + reg;
                    Uhat[(size_t)(b * 128 + m) * LF + l0 + n] =
                        make_float2(accR[s][t][reg] - accM[s][t][reg], accI[s][t][reg]);
                }
            }
        }
    }
}

// ---------------------------------------------------------------------------
extern "C" void kernel_launch(void* const* d_in, const int* in_sizes, int n_in,
                              void* d_out, int out_size, void* d_ws, size_t ws_size,
                              hipStream_t stream) {
    const float* u    = (const float*)d_in[0];   // (B,H,L)
    const float* C_ri = (const float*)d_in[1];   // (H,P,2)
    const float* D_ri = (const float*)d_in[2];   // (H,H,2)
    const float* B_ri = (const float*)d_in[3];   // (P,H,2)
    const float* Lam  = (const float*)d_in[4];   // (P,2)
    float* out = (float*)d_out;

    float2* Uhat = (float2*)d_ws;                          // 1024*2049 float2 = 16 MiB
    _Float16* W1 = (_Float16*)(Uhat + (size_t)NROWS * LF);
    _Float16* W2 = W1 + 2 * WPLSZ;
    _Float16* W3 = W2 + 2 * WPLSZ;
    float2* Em = (float2*)(W3 + 2 * WPLSZ);

    prep_ABE_k<<<192, 256, 0, stream>>>(B_ri, C_ri, D_ri, W1, W2, Em);
    prep_W3_k<<<64, 256, 0, stream>>>(Em, W3);

    rfft_rows_k<<<NROWS, 256, 0, stream>>>(u, Uhat);
    mixmm_k<<<Bn * NTILES, 256, 0, stream>>>(Uhat, W1, W2, W3, Lam);
    irfft_gelu_k<<<NROWS, 256, 0, stream>>>(Uhat, out);
}